// Round 1
// 628.059 us; speedup vs baseline: 1.0099x; 1.0099x over previous
//
#include <hip/hip_runtime.h>
#include <math.h>

#define H 1024
#define NHEAD 16
#define HDIM 64
#define IDIM 4096
#define BATCH 4
#define SEQ 2048
#define NTOK 8192
#define LN_EPS 1e-5f

// 0.125 * log2(e): folded into Q at QKV-GEMM epilogue so attention's softmax
// is a raw v_exp_f32 (2^x) with zero preceding VALU muls.
#define QK_EXP2_SCALE 0.18033688011112042f

typedef __bf16 bf16x8 __attribute__((ext_vector_type(8)));
typedef __bf16 bf16x4 __attribute__((ext_vector_type(4)));
typedef float f32x4 __attribute__((ext_vector_type(4)));
typedef unsigned short ushort8 __attribute__((ext_vector_type(8)));
typedef unsigned short ushort4v __attribute__((ext_vector_type(4)));

__device__ __forceinline__ unsigned short f2bf(float f) {
  union { float f; unsigned int u; } v; v.f = f;
  unsigned int u = v.u;
  return (unsigned short)((u + 0x7FFFu + ((u >> 16) & 1u)) >> 16);
}

// ---------- transpose + cast: W[K][N] f32 -> Wt[N][K] bf16 ----------
__global__ void transpose_cast_kernel(const float* __restrict__ W,
                                      unsigned short* __restrict__ Wt,
                                      int K, int N) {
  __shared__ unsigned short tile[32][33];
  int n0 = blockIdx.x * 32, k0 = blockIdx.y * 32;
  int tx = threadIdx.x, ty = threadIdx.y;  // 32 x 8
#pragma unroll
  for (int i = 0; i < 4; i++) {
    int k = ty + i * 8;
    tile[tx][k] = f2bf(W[(size_t)(k0 + k) * N + n0 + tx]);
  }
  __syncthreads();
#pragma unroll
  for (int i = 0; i < 4; i++) {
    int n = ty + i * 8;
    Wt[(size_t)(n0 + n) * K + k0 + tx] = tile[n][tx];
  }
}

// ---------- layernorm: f32 [rows][H] -> bf16 ----------
__global__ __launch_bounds__(256)
void layernorm_kernel(const float* __restrict__ x, const float* __restrict__ g,
                      const float* __restrict__ b, unsigned short* __restrict__ out) {
  __shared__ float sb[4];
  int row = blockIdx.x;
  int tid = threadIdx.x;
  const float4* xr = (const float4*)(x + (size_t)row * H);
  float4 v = xr[tid];
  float s = v.x + v.y + v.z + v.w;
#pragma unroll
  for (int o = 32; o > 0; o >>= 1) s += __shfl_down(s, o);
  if ((tid & 63) == 0) sb[tid >> 6] = s;
  __syncthreads();
  float mu = (sb[0] + sb[1] + sb[2] + sb[3]) * (1.0f / H);
  __syncthreads();
  float dx = v.x - mu, dy = v.y - mu, dz = v.z - mu, dw = v.w - mu;
  float s2 = dx * dx + dy * dy + dz * dz + dw * dw;
#pragma unroll
  for (int o = 32; o > 0; o >>= 1) s2 += __shfl_down(s2, o);
  if ((tid & 63) == 0) sb[tid >> 6] = s2;
  __syncthreads();
  float var = (sb[0] + sb[1] + sb[2] + sb[3]) * (1.0f / H);
  float rs = rsqrtf(var + LN_EPS);
  float4 gv = ((const float4*)g)[tid];
  float4 bv = ((const float4*)b)[tid];
  ushort4v ov;
  ov[0] = f2bf(dx * rs * gv.x + bv.x);
  ov[1] = f2bf(dy * rs * gv.y + bv.y);
  ov[2] = f2bf(dz * rs * gv.z + bv.z);
  ov[3] = f2bf(dw * rs * gv.w + bv.w);
  ((ushort4v*)(out + (size_t)row * H))[tid] = ov;
}

// ---------- GEMM: C = A(bf16,[M][K]) @ Bt(bf16,[N][K])^T + bias ----------
// Single-barrier double-buffered K-loop: tile k+1's global_load_lds issued
// right after the barrier that publishes tile k; the NEXT iteration's barrier
// (implicit vmcnt(0) drain) is the wait -> staging gets a full compute phase
// in flight, and barrier count halves vs the 2-barrier m97 structure.
// MFMA computes C^T (lane owns row m=l16, reg r = 4 consecutive N cols).
// EPI 0: bf16 (q-slice pre-scaled by QK_EXP2_SCALE; opt fused V-transpose for
// QKV v-slice); 1: bf16 gelu; 2: f32+res.
template <int EPI>
__global__ __launch_bounds__(256)
void gemm_bt_kernel(const unsigned short* __restrict__ A,
                    const unsigned short* __restrict__ Bt,
                    const float* __restrict__ bias,
                    const float* __restrict__ res,
                    void* __restrict__ out, unsigned short* __restrict__ vt_out,
                    int M, int N, int K) {
  __shared__ __align__(16) unsigned short As[2][128 * 32];
  __shared__ __align__(16) unsigned short Bs[2][128 * 32];
  int tid = threadIdx.x;
  int wave = tid >> 6, lane = tid & 63;
  int quad = lane >> 4, l16 = lane & 15;
  int wm = wave >> 1, wn = wave & 1;
  int m0 = blockIdx.y * 128, n0 = blockIdx.x * 128;
  f32x4 acc[4][4];  // [i=m strip][j=n strip]; reg r = n offset (C^T layout)
#pragma unroll
  for (int i = 0; i < 4; i++)
#pragma unroll
    for (int j = 0; j < 4; j++) acc[i][j] = (f32x4){0.f, 0.f, 0.f, 0.f};

  int rl = (lane >> 2);
  int cphys = lane & 3;

  auto stage = [&](int k0, int sel) {
#pragma unroll
    for (int t = 0; t < 2; t++) {
      int ch = wave * 2 + t;
      int rloc = ch * 16 + rl;
      int clog = cphys ^ ((rloc >> 1) & 3);
      const unsigned short* ga = A + (size_t)(m0 + rloc) * K + k0 + clog * 8;
      __builtin_amdgcn_global_load_lds(
          (const __attribute__((address_space(1))) unsigned int*)ga,
          (__attribute__((address_space(3))) unsigned int*)(&As[sel][ch * 512]), 16, 0, 0);
      const unsigned short* gb = Bt + (size_t)(n0 + rloc) * K + k0 + clog * 8;
      __builtin_amdgcn_global_load_lds(
          (const __attribute__((address_space(1))) unsigned int*)gb,
          (__attribute__((address_space(3))) unsigned int*)(&Bs[sel][ch * 512]), 16, 0, 0);
    }
  };

  stage(0, 0);  // prologue
  for (int k0 = 0; k0 < K; k0 += 32) {
    int sel = (k0 >> 5) & 1;
    // single barrier: vmcnt(0) drain = wait for tile k0's staging (issued one
    // full iteration ago); lgkm drain = all waves done reading buf sel^1.
    __syncthreads();
    if (k0 + 32 < K) stage(k0 + 32, sel ^ 1);
    bf16x8 af[4], bfv[4];
#pragma unroll
    for (int i = 0; i < 4; i++) {
      int ra = wm * 64 + i * 16 + l16;
      af[i] = *(const bf16x8*)&As[sel][ra * 32 + ((quad ^ ((ra >> 1) & 3)) << 3)];
      int rb = wn * 64 + i * 16 + l16;
      bfv[i] = *(const bf16x8*)&Bs[sel][rb * 32 + ((quad ^ ((rb >> 1) & 3)) << 3)];
    }
#pragma unroll
    for (int i = 0; i < 4; i++)
#pragma unroll
      for (int j = 0; j < 4; j++)
        acc[i][j] = __builtin_amdgcn_mfma_f32_16x16x32_bf16(bfv[j], af[i], acc[i][j], 0, 0, 0);
  }
  // epilogue: lane = row m (l16), reg r = col n offset (quad*4+r)
  bool vslice = (EPI == 0) && (vt_out != nullptr) && (n0 >= 2 * H);
#pragma unroll
  for (int i = 0; i < 4; i++) {
    int m = m0 + wm * 64 + i * 16 + l16;
#pragma unroll
    for (int j = 0; j < 4; j++) {
      int nb = n0 + wn * 64 + j * 16 + quad * 4;
      float4 bv4 = *(const float4*)&bias[nb];
      float v0 = acc[i][j][0] + bv4.x;
      float v1 = acc[i][j][1] + bv4.y;
      float v2 = acc[i][j][2] + bv4.z;
      float v3 = acc[i][j][3] + bv4.w;
      size_t off = (size_t)m * N + nb;
      if (EPI == 0) {
        if (vslice) {
          // write vt[bh][d][s] transposed; skip the qkvb row write
          int bb = m >> 11, s = m & (SEQ - 1);
          int cb = nb - 2 * H;
          int hh = cb >> 6, dd = cb & 63;
          size_t base = ((size_t)(bb * NHEAD + hh) * HDIM + dd) * SEQ + s;
          vt_out[base] = f2bf(v0);
          vt_out[base + SEQ] = f2bf(v1);
          vt_out[base + 2 * SEQ] = f2bf(v2);
          vt_out[base + 3 * SEQ] = f2bf(v3);
        } else {
          // q-slice (n0 < H): fold softmax scale * log2(e) into Q so the
          // attention kernel's exp is a bare v_exp_f32 (saves 2 muls/elem).
          if (n0 < H) {
            v0 *= QK_EXP2_SCALE; v1 *= QK_EXP2_SCALE;
            v2 *= QK_EXP2_SCALE; v3 *= QK_EXP2_SCALE;
          }
          bf16x4 pk = {(__bf16)v0, (__bf16)v1, (__bf16)v2, (__bf16)v3};
          *(bf16x4*)&((unsigned short*)out)[off] = pk;
        }
      } else if (EPI == 1) {
        float g0 = v0 / (1.f + __expf(-1.5957691216057308f * (v0 + 0.044715f * v0 * v0 * v0)));
        float g1 = v1 / (1.f + __expf(-1.5957691216057308f * (v1 + 0.044715f * v1 * v1 * v1)));
        float g2 = v2 / (1.f + __expf(-1.5957691216057308f * (v2 + 0.044715f * v2 * v2 * v2)));
        float g3 = v3 / (1.f + __expf(-1.5957691216057308f * (v3 + 0.044715f * v3 * v3 * v3)));
        bf16x4 pk = {(__bf16)g0, (__bf16)g1, (__bf16)g2, (__bf16)g3};
        *(bf16x4*)&((unsigned short*)out)[off] = pk;
      } else {
        float4 rv = *(const float4*)&res[off];
        float4 o4;
        o4.x = v0 + rv.x; o4.y = v1 + rv.y; o4.z = v2 + rv.z; o4.w = v3 + rv.w;
        *(float4*)&((float*)out)[off] = o4;
      }
    }
  }
}

// ---------- flash attention v8: v7 + XCD-bh swizzle + exp2 + setprio ----------
// Block = 4 waves, BQ=128 (wave owns 32 q), BKV=64, grid 1024 blocks (1-D).
// XCD swizzle (T1 form, bijective: 1024 = 8*128): hardware round-robins
// dispatch index d over XCDs, so logical = (d%8)*128 + d/8 gives XCD j the
// logical range [j*128, (j+1)*128) = heads [j*8, j*8+8) x all 16 q-blocks.
// Per-XCD L2 working set = 8*(256KB vt + 256KB K) = 4MB -> va loads and K
// staging become L2 hits instead of ~900-cyc HBM misses (FETCH was 139MB vs
// ~48MB unique).
// Softmax: Q pre-scaled by 0.125*log2(e) in the QKV GEMM, so P = 2^st via a
// bare v_exp_f32 (no muls). Max-free (|st| << 88). s_setprio(1) wraps both
// MFMA clusters (T5: independent blocks per CU -> scheduler has role split).
// Ks double-buffered, single barrier per iter (implicit vmcnt(0) is the wait
// for the stage issued one iteration ago). va (V reg frags) issued before the
// stage. S^T = mfma(K_a, Q_b); P kv-contig -> packed ds_write_b64; PV per
// 32-kv half with partial lgkm drains.
// LPs=40: bank mapping stays at the HW minimum (8/bank b128, 4/bank b64).
__global__ __launch_bounds__(256)
void flash_attn_kernel(const unsigned short* __restrict__ qkv,
                       const unsigned short* __restrict__ vt,
                       unsigned short* __restrict__ attn_out) {
  constexpr int LPs = 40;
  __shared__ __align__(16) unsigned short Ks[2][64 * 64];
  __shared__ __align__(16) unsigned short Ps[4 * 32 * LPs];
  int tid = threadIdx.x;
  int wave = tid >> 6, lane = tid & 63;
  int quad = lane >> 4, l16 = lane & 15;
  int d = blockIdx.x;
  int logical = (d & 7) * 128 + (d >> 3);  // XCD-bh grouping (see header)
  int bh = logical >> 4, qi = logical & 15;
  int b = bh >> 4, h = bh & 15;
  int qblk = qi * 128 + wave * 32;
  const size_t qrow = 3 * H;
  const size_t tok0 = (size_t)b * SEQ;
  const size_t vbase = (size_t)bh * HDIM * SEQ;
  unsigned short* Psw = Ps + wave * 32 * LPs;

  // Q B-fragments (q on l16), register-resident for the whole loop
  bf16x8 qb[2][2];
#pragma unroll
  for (int mb = 0; mb < 2; mb++)
#pragma unroll
    for (int ks = 0; ks < 2; ks++)
      qb[mb][ks] = *(const bf16x8*)&qkv[(tok0 + qblk + mb * 16 + l16) * qrow +
                                        h * HDIM + ks * 32 + quad * 8];

  float l_part[2] = {0.f, 0.f};
  f32x4 o_acc[2][4];  // [mb][db], O^T layout (rows d, cols q)
#pragma unroll
  for (int mb = 0; mb < 2; mb++)
#pragma unroll
    for (int db = 0; db < 4; db++) o_acc[mb][db] = (f32x4){0.f, 0.f, 0.f, 0.f};

  int srow = lane >> 3;            // 0..7: row within 8-row staging group
  int schunk = (lane & 7) ^ srow;  // swizzled 16B source chunk

  // prologue: stage tile 0 into buf 0
#pragma unroll
  for (int t = 0; t < 2; t++) {
    int rbase = wave * 16 + t * 8;
    const unsigned short* ga =
        &qkv[(tok0 + rbase + srow) * qrow + H + h * HDIM + schunk * 8];
    __builtin_amdgcn_global_load_lds(
        (const __attribute__((address_space(1))) unsigned int*)ga,
        (__attribute__((address_space(3))) unsigned int*)(&Ks[0][rbase * 64]), 16, 0, 0);
  }

  for (int kv0 = 0; kv0 < SEQ; kv0 += 64) {
    int buf = (kv0 >> 6) & 1;
    const unsigned short* Kb = Ks[buf];
    unsigned short* Kn = Ks[buf ^ 1];
    __syncthreads();  // vmcnt(0) drain = Ks[buf] staged; fences Kn readers
    // V A-fragments for this tile — issued BEFORE next-tile stage so the
    // PV-side wait on them leaves the stage outstanding
    bf16x8 va[4][2];
#pragma unroll
    for (int db = 0; db < 4; db++)
#pragma unroll
      for (int ks = 0; ks < 2; ks++)
        va[db][ks] = *(const bf16x8*)&vt[vbase + (size_t)(db * 16 + l16) * SEQ +
                                         kv0 + ks * 32 + quad * 8];
    if (kv0 + 64 < SEQ) {
#pragma unroll
      for (int t = 0; t < 2; t++) {
        int rbase = wave * 16 + t * 8;
        const unsigned short* ga =
            &qkv[(tok0 + kv0 + 64 + rbase + srow) * qrow + H + h * HDIM + schunk * 8];
        __builtin_amdgcn_global_load_lds(
            (const __attribute__((address_space(1))) unsigned int*)ga,
            (__attribute__((address_space(3))) unsigned int*)(Kn + rbase * 64), 16, 0, 0);
      }
    }
    // per 32-kv half: S^T strips -> exp/pack -> partial drain -> PV
#pragma unroll
    for (int half = 0; half < 2; half++) {
#pragma unroll
      for (int nbl = 0; nbl < 2; nbl++) {
        int nb = half * 2 + nbl;
        int row = nb * 16 + l16;
        bf16x8 ka[2];
#pragma unroll
        for (int ks = 0; ks < 2; ks++) {
          int pc = (ks * 4 + quad) ^ (row & 7);
          ka[ks] = *(const bf16x8*)&Kb[row * 64 + pc * 8];
        }
        f32x4 st[2];
#pragma unroll
        for (int mb = 0; mb < 2; mb++) st[mb] = (f32x4){0.f, 0.f, 0.f, 0.f};
        __builtin_amdgcn_s_setprio(1);
#pragma unroll
        for (int ks = 0; ks < 2; ks++)
#pragma unroll
          for (int mb = 0; mb < 2; mb++)
            st[mb] = __builtin_amdgcn_mfma_f32_16x16x32_bf16(ka[ks], qb[mb][ks], st[mb], 0, 0, 0);
        __builtin_amdgcn_s_setprio(0);
#pragma unroll
        for (int mb = 0; mb < 2; mb++) {
          // Q was pre-scaled by 0.125*log2(e): P = 2^st, bare v_exp_f32.
          float p0, p1, p2, p3;
          asm("v_exp_f32 %0, %1" : "=v"(p0) : "v"(st[mb][0]));
          asm("v_exp_f32 %0, %1" : "=v"(p1) : "v"(st[mb][1]));
          asm("v_exp_f32 %0, %1" : "=v"(p2) : "v"(st[mb][2]));
          asm("v_exp_f32 %0, %1" : "=v"(p3) : "v"(st[mb][3]));
          l_part[mb] += (p0 + p1) + (p2 + p3);
          bf16x4 pk = {(__bf16)p0, (__bf16)p1, (__bf16)p2, (__bf16)p3};
          *(bf16x4*)&Psw[(mb * 16 + l16) * LPs + nb * 16 + quad * 4] = pk;
        }
      }
      // drain our wave's Ps writes for this half (wave-private, no barrier)
      __asm__ volatile("s_waitcnt lgkmcnt(0)" ::: "memory");
      bf16x8 pb[2];
#pragma unroll
      for (int mb = 0; mb < 2; mb++)
        pb[mb] = *(const bf16x8*)&Psw[(mb * 16 + l16) * LPs + half * 32 + quad * 8];
      __builtin_amdgcn_s_setprio(1);
#pragma unroll
      for (int db = 0; db < 4; db++)
#pragma unroll
        for (int mb = 0; mb < 2; mb++)
          o_acc[mb][db] = __builtin_amdgcn_mfma_f32_16x16x32_bf16(va[db][half], pb[mb],
                                                                  o_acc[mb][db], 0, 0, 0);
      __builtin_amdgcn_s_setprio(0);
    }
  }
  // reduce l across the 4 quads; lane then holds inv-l for its own q = mb*16+l16
#pragma unroll
  for (int mb = 0; mb < 2; mb++) {
    l_part[mb] += __shfl_xor(l_part[mb], 16);
    l_part[mb] += __shfl_xor(l_part[mb], 32);
    l_part[mb] = 1.0f / l_part[mb];
  }
  // O^T C-layout: col q = mb*16+l16, rows d = db*16+quad*4+r (contig) -> 8B stores
#pragma unroll
  for (int mb = 0; mb < 2; mb++) {
#pragma unroll
    for (int db = 0; db < 4; db++) {
      ushort4v o;
#pragma unroll
      for (int r = 0; r < 4; r++) o[r] = f2bf(o_acc[mb][db][r] * l_part[mb]);
      *(ushort4v*)&attn_out[(tok0 + qblk + mb * 16 + l16) * H + h * HDIM +
                            db * 16 + quad * 4] = o;
    }
  }
}

extern "C" void kernel_launch(void* const* d_in, const int* in_sizes, int n_in,
                              void* d_out, int out_size, void* d_ws, size_t ws_size,
                              hipStream_t stream) {
  const float* x = (const float*)d_in[0];
  const float* ln1_g = (const float*)d_in[1];
  const float* ln1_b = (const float*)d_in[2];
  const float* qkv_w = (const float*)d_in[3];
  const float* qkv_b = (const float*)d_in[4];
  const float* out_w = (const float*)d_in[5];
  const float* out_b = (const float*)d_in[6];
  const float* ln2_g = (const float*)d_in[7];
  const float* ln2_b = (const float*)d_in[8];
  const float* w1 = (const float*)d_in[9];
  const float* b1 = (const float*)d_in[10];
  const float* w2 = (const float*)d_in[11];
  const float* b2 = (const float*)d_in[12];
  float* outp = (float*)d_out;

  size_t off = 0;
  auto take = [&](size_t n) {
    char* p = (char*)d_ws + off;
    off += (n + 255) & ~(size_t)255;
    return p;
  };
  unsigned short* h1 = (unsigned short*)take((size_t)NTOK * H * 2);       // also h2
  unsigned short* qkvb = (unsigned short*)take((size_t)NTOK * 3 * H * 2); // qkv; later mid
  unsigned short* attn = (unsigned short*)take((size_t)NTOK * H * 2);
  float* x1 = (float*)take((size_t)NTOK * H * 4);
  unsigned short* qkvwt = (unsigned short*)take((size_t)3 * H * H * 2);
  unsigned short* outwt = (unsigned short*)take((size_t)H * H * 2);
  unsigned short* w1t = (unsigned short*)take((size_t)H * IDIM * 2);
  unsigned short* w2t = (unsigned short*)take((size_t)H * IDIM * 2);
  unsigned short* h2 = h1;
  unsigned short* mid = qkvb;                // [NTOK][IDIM] aliases qkv+attn exactly
  unsigned short* vt = (unsigned short*)x1;  // vt dead before proj writes x1

  dim3 tb(32, 8);
  transpose_cast_kernel<<<dim3(3 * H / 32, H / 32), tb, 0, stream>>>(qkv_w, qkvwt, H, 3 * H);
  transpose_cast_kernel<<<dim3(H / 32, H / 32), tb, 0, stream>>>(out_w, outwt, H, H);
  transpose_cast_kernel<<<dim3(IDIM / 32, H / 32), tb, 0, stream>>>(w1, w1t, H, IDIM);
  transpose_cast_kernel<<<dim3(H / 32, IDIM / 32), tb, 0, stream>>>(w2, w2t, IDIM, H);

  layernorm_kernel<<<NTOK, 256, 0, stream>>>(x, ln1_g, ln1_b, h1);
  // QKV GEMM; v-slice blocks (n0>=2H) write vt transposed directly
  gemm_bt_kernel<0><<<dim3(3 * H / 128, NTOK / 128), 256, 0, stream>>>(
      h1, qkvwt, qkv_b, nullptr, qkvb, vt, NTOK, 3 * H, H);
  // 1-D grid: in-kernel XCD-bh swizzle (1024 blocks = 8 XCD x 128)
  flash_attn_kernel<<<dim3(SEQ / 128 * BATCH * NHEAD), 256, 0, stream>>>(qkvb, vt, attn);
  gemm_bt_kernel<2><<<dim3(H / 128, NTOK / 128), 256, 0, stream>>>(
      attn, outwt, out_b, x, x1, nullptr, NTOK, H, H);
  layernorm_kernel<<<NTOK, 256, 0, stream>>>(x1, ln2_g, ln2_b, h2);
  gemm_bt_kernel<1><<<dim3(IDIM / 128, NTOK / 128), 256, 0, stream>>>(
      h2, w1t, b1, nullptr, mid, nullptr, NTOK, IDIM, H);
  gemm_bt_kernel<2><<<dim3(H / 128, NTOK / 128), 256, 0, stream>>>(
      mid, w2t, b2, x1, outp, nullptr, NTOK, H, IDIM);
}

// Round 2
// 623.912 us; speedup vs baseline: 1.0166x; 1.0066x over previous
//
#include <hip/hip_runtime.h>
#include <math.h>

#define H 1024
#define NHEAD 16
#define HDIM 64
#define IDIM 4096
#define BATCH 4
#define SEQ 2048
#define NTOK 8192
#define LN_EPS 1e-5f

// 0.125 * log2(e): folded into Q at QKV-GEMM epilogue so attention's softmax
// is a raw v_exp_f32 (2^x) with zero preceding VALU muls.
#define QK_EXP2_SCALE 0.18033688011112042f

typedef __bf16 bf16x8 __attribute__((ext_vector_type(8)));
typedef __bf16 bf16x4 __attribute__((ext_vector_type(4)));
typedef float f32x4 __attribute__((ext_vector_type(4)));
typedef unsigned short ushort8 __attribute__((ext_vector_type(8)));
typedef unsigned short ushort4v __attribute__((ext_vector_type(4)));

__device__ __forceinline__ unsigned short f2bf(float f) {
  union { float f; unsigned int u; } v; v.f = f;
  unsigned int u = v.u;
  return (unsigned short)((u + 0x7FFFu + ((u >> 16) & 1u)) >> 16);
}

// ---------- transpose + cast: W[K][N] f32 -> Wt[N][K] bf16 ----------
__global__ void transpose_cast_kernel(const float* __restrict__ W,
                                      unsigned short* __restrict__ Wt,
                                      int K, int N) {
  __shared__ unsigned short tile[32][33];
  int n0 = blockIdx.x * 32, k0 = blockIdx.y * 32;
  int tx = threadIdx.x, ty = threadIdx.y;  // 32 x 8
#pragma unroll
  for (int i = 0; i < 4; i++) {
    int k = ty + i * 8;
    tile[tx][k] = f2bf(W[(size_t)(k0 + k) * N + n0 + tx]);
  }
  __syncthreads();
#pragma unroll
  for (int i = 0; i < 4; i++) {
    int n = ty + i * 8;
    Wt[(size_t)(n0 + n) * K + k0 + tx] = tile[n][tx];
  }
}

// ---------- layernorm: f32 [rows][H] -> bf16 ----------
__global__ __launch_bounds__(256)
void layernorm_kernel(const float* __restrict__ x, const float* __restrict__ g,
                      const float* __restrict__ b, unsigned short* __restrict__ out) {
  __shared__ float sb[4];
  int row = blockIdx.x;
  int tid = threadIdx.x;
  const float4* xr = (const float4*)(x + (size_t)row * H);
  float4 v = xr[tid];
  float s = v.x + v.y + v.z + v.w;
#pragma unroll
  for (int o = 32; o > 0; o >>= 1) s += __shfl_down(s, o);
  if ((tid & 63) == 0) sb[tid >> 6] = s;
  __syncthreads();
  float mu = (sb[0] + sb[1] + sb[2] + sb[3]) * (1.0f / H);
  __syncthreads();
  float dx = v.x - mu, dy = v.y - mu, dz = v.z - mu, dw = v.w - mu;
  float s2 = dx * dx + dy * dy + dz * dz + dw * dw;
#pragma unroll
  for (int o = 32; o > 0; o >>= 1) s2 += __shfl_down(s2, o);
  if ((tid & 63) == 0) sb[tid >> 6] = s2;
  __syncthreads();
  float var = (sb[0] + sb[1] + sb[2] + sb[3]) * (1.0f / H);
  float rs = rsqrtf(var + LN_EPS);
  float4 gv = ((const float4*)g)[tid];
  float4 bv = ((const float4*)b)[tid];
  ushort4v ov;
  ov[0] = f2bf(dx * rs * gv.x + bv.x);
  ov[1] = f2bf(dy * rs * gv.y + bv.y);
  ov[2] = f2bf(dz * rs * gv.z + bv.z);
  ov[3] = f2bf(dw * rs * gv.w + bv.w);
  ((ushort4v*)(out + (size_t)row * H))[tid] = ov;
}

// ---------- GEMM: C = A(bf16,[M][K]) @ Bt(bf16,[N][K])^T + bias ----------
// Single-barrier double-buffered K-loop: tile k+1's global_load_lds issued
// right after the barrier that publishes tile k; the NEXT iteration's barrier
// (implicit vmcnt(0) drain) is the wait -> staging gets a full compute phase
// in flight, and barrier count halves vs the 2-barrier m97 structure.
// MFMA computes C^T (lane owns row m=l16, reg r = 4 consecutive N cols).
// EPI 0: bf16 (q-slice pre-scaled by QK_EXP2_SCALE; opt fused V-transpose for
// QKV v-slice); 1: bf16 gelu; 2: f32+res.
template <int EPI>
__global__ __launch_bounds__(256)
void gemm_bt_kernel(const unsigned short* __restrict__ A,
                    const unsigned short* __restrict__ Bt,
                    const float* __restrict__ bias,
                    const float* __restrict__ res,
                    void* __restrict__ out, unsigned short* __restrict__ vt_out,
                    int M, int N, int K) {
  __shared__ __align__(16) unsigned short As[2][128 * 32];
  __shared__ __align__(16) unsigned short Bs[2][128 * 32];
  int tid = threadIdx.x;
  int wave = tid >> 6, lane = tid & 63;
  int quad = lane >> 4, l16 = lane & 15;
  int wm = wave >> 1, wn = wave & 1;
  int m0 = blockIdx.y * 128, n0 = blockIdx.x * 128;
  f32x4 acc[4][4];  // [i=m strip][j=n strip]; reg r = n offset (C^T layout)
#pragma unroll
  for (int i = 0; i < 4; i++)
#pragma unroll
    for (int j = 0; j < 4; j++) acc[i][j] = (f32x4){0.f, 0.f, 0.f, 0.f};

  int rl = (lane >> 2);
  int cphys = lane & 3;

  auto stage = [&](int k0, int sel) {
#pragma unroll
    for (int t = 0; t < 2; t++) {
      int ch = wave * 2 + t;
      int rloc = ch * 16 + rl;
      int clog = cphys ^ ((rloc >> 1) & 3);
      const unsigned short* ga = A + (size_t)(m0 + rloc) * K + k0 + clog * 8;
      __builtin_amdgcn_global_load_lds(
          (const __attribute__((address_space(1))) unsigned int*)ga,
          (__attribute__((address_space(3))) unsigned int*)(&As[sel][ch * 512]), 16, 0, 0);
      const unsigned short* gb = Bt + (size_t)(n0 + rloc) * K + k0 + clog * 8;
      __builtin_amdgcn_global_load_lds(
          (const __attribute__((address_space(1))) unsigned int*)gb,
          (__attribute__((address_space(3))) unsigned int*)(&Bs[sel][ch * 512]), 16, 0, 0);
    }
  };

  stage(0, 0);  // prologue
  for (int k0 = 0; k0 < K; k0 += 32) {
    int sel = (k0 >> 5) & 1;
    // single barrier: vmcnt(0) drain = wait for tile k0's staging (issued one
    // full iteration ago); lgkm drain = all waves done reading buf sel^1.
    __syncthreads();
    if (k0 + 32 < K) stage(k0 + 32, sel ^ 1);
    bf16x8 af[4], bfv[4];
#pragma unroll
    for (int i = 0; i < 4; i++) {
      int ra = wm * 64 + i * 16 + l16;
      af[i] = *(const bf16x8*)&As[sel][ra * 32 + ((quad ^ ((ra >> 1) & 3)) << 3)];
      int rb = wn * 64 + i * 16 + l16;
      bfv[i] = *(const bf16x8*)&Bs[sel][rb * 32 + ((quad ^ ((rb >> 1) & 3)) << 3)];
    }
#pragma unroll
    for (int i = 0; i < 4; i++)
#pragma unroll
      for (int j = 0; j < 4; j++)
        acc[i][j] = __builtin_amdgcn_mfma_f32_16x16x32_bf16(bfv[j], af[i], acc[i][j], 0, 0, 0);
  }
  // epilogue: lane = row m (l16), reg r = col n offset (quad*4+r)
  bool vslice = (EPI == 0) && (vt_out != nullptr) && (n0 >= 2 * H);
#pragma unroll
  for (int i = 0; i < 4; i++) {
    int m = m0 + wm * 64 + i * 16 + l16;
#pragma unroll
    for (int j = 0; j < 4; j++) {
      int nb = n0 + wn * 64 + j * 16 + quad * 4;
      float4 bv4 = *(const float4*)&bias[nb];
      float v0 = acc[i][j][0] + bv4.x;
      float v1 = acc[i][j][1] + bv4.y;
      float v2 = acc[i][j][2] + bv4.z;
      float v3 = acc[i][j][3] + bv4.w;
      size_t off = (size_t)m * N + nb;
      if (EPI == 0) {
        if (vslice) {
          // write vt[bh][d][s] transposed; skip the qkvb row write
          int bb = m >> 11, s = m & (SEQ - 1);
          int cb = nb - 2 * H;
          int hh = cb >> 6, dd = cb & 63;
          size_t base = ((size_t)(bb * NHEAD + hh) * HDIM + dd) * SEQ + s;
          vt_out[base] = f2bf(v0);
          vt_out[base + SEQ] = f2bf(v1);
          vt_out[base + 2 * SEQ] = f2bf(v2);
          vt_out[base + 3 * SEQ] = f2bf(v3);
        } else {
          // q-slice (n0 < H): fold softmax scale * log2(e) into Q so the
          // attention kernel's exp is a bare v_exp_f32 (saves 2 muls/elem).
          if (n0 < H) {
            v0 *= QK_EXP2_SCALE; v1 *= QK_EXP2_SCALE;
            v2 *= QK_EXP2_SCALE; v3 *= QK_EXP2_SCALE;
          }
          bf16x4 pk = {(__bf16)v0, (__bf16)v1, (__bf16)v2, (__bf16)v3};
          *(bf16x4*)&((unsigned short*)out)[off] = pk;
        }
      } else if (EPI == 1) {
        float g0 = v0 / (1.f + __expf(-1.5957691216057308f * (v0 + 0.044715f * v0 * v0 * v0)));
        float g1 = v1 / (1.f + __expf(-1.5957691216057308f * (v1 + 0.044715f * v1 * v1 * v1)));
        float g2 = v2 / (1.f + __expf(-1.5957691216057308f * (v2 + 0.044715f * v2 * v2 * v2)));
        float g3 = v3 / (1.f + __expf(-1.5957691216057308f * (v3 + 0.044715f * v3 * v3 * v3)));
        bf16x4 pk = {(__bf16)g0, (__bf16)g1, (__bf16)g2, (__bf16)g3};
        *(bf16x4*)&((unsigned short*)out)[off] = pk;
      } else {
        float4 rv = *(const float4*)&res[off];
        float4 o4;
        o4.x = v0 + rv.x; o4.y = v1 + rv.y; o4.z = v2 + rv.z; o4.w = v3 + rv.w;
        *(float4*)&((float*)out)[off] = o4;
      }
    }
  }
}

// ---------- flash attention v9: v8 + split-KV + l via ones-MFMA ----------
// Block = 4 waves, BQ=128 (wave owns 32 q), BKV=64.
// NSPLIT=2: grid 2048 (64 bh x 16 qi x 2 kv-halves); each block does 1024 kv
// and writes UNNORMALIZED f32 O-partials + l-partials (max-free softmax makes
// the combine a plain (O0+O1)/(l0+l1)). Grid 1024->2048 lifts the blocks/CU
// cap from 4 (grid-limited, 35% occ measured) toward the LDS limit of 6.
// NSPLIT=1: fallback (ws too small) = R1 behavior, direct bf16 write.
// l via ones-MFMA: l_acc[mb] = mfma(ones, pb[mb], l_acc[mb]) — all-ones A
// makes every output row = sum_k P[k][q]. Replaces 32 VALU adds/iter/wave
// with 4 MFMAs on the 17%-busy matrix pipe, and every lane ends holding l[q]
// (no end-of-kernel shfl reduce).
// XCD swizzle bijective (grid % 8 == 0): XCD j owns heads [j*8, j*8+8).
// Softmax: Q pre-scaled by 0.125*log2(e) -> bare v_exp_f32. setprio(1) wraps
// MFMA clusters. Ks double-buffered, single barrier per iter (implicit
// vmcnt(0) is the wait for the stage issued one iteration ago). va issued
// before the stage so its vmcnt wait leaves the stage outstanding.
// LPs=40: P rows overlap-compressed (half0 region dead before half1 writes).
template <int NSPLIT>
__global__ __launch_bounds__(256)
void flash_attn_kernel(const unsigned short* __restrict__ qkv,
                       const unsigned short* __restrict__ vt,
                       unsigned short* __restrict__ attn_out,
                       float* __restrict__ opart, float* __restrict__ lsum) {
  constexpr int LPs = 40;
  constexpr int KVLEN = SEQ / NSPLIT;
  constexpr int CHUNK = (SEQ / 128) * BATCH * NHEAD * NSPLIT / 8;  // blocks/XCD
  __shared__ __align__(16) unsigned short Ks[2][64 * 64];
  __shared__ __align__(16) unsigned short Ps[4 * 32 * LPs];
  int tid = threadIdx.x;
  int wave = tid >> 6, lane = tid & 63;
  int quad = lane >> 4, l16 = lane & 15;
  int d = blockIdx.x;
  int logical = (d & 7) * CHUNK + (d >> 3);  // XCD-bh grouping
  int bh, qi, sp;
  if (NSPLIT == 2) {
    bh = logical >> 5;
    int rem = logical & 31;
    qi = rem >> 1;
    sp = rem & 1;
  } else {
    bh = logical >> 4;
    qi = logical & 15;
    sp = 0;
  }
  int b = bh >> 4, h = bh & 15;
  int qblk = qi * 128 + wave * 32;
  int kvbase = sp * KVLEN;
  const size_t qrow = 3 * H;
  const size_t tok0 = (size_t)b * SEQ;
  const size_t vbase = (size_t)bh * HDIM * SEQ;
  unsigned short* Psw = Ps + wave * 32 * LPs;

  // Q B-fragments (q on l16), register-resident for the whole loop
  bf16x8 qb[2][2];
#pragma unroll
  for (int mb = 0; mb < 2; mb++)
#pragma unroll
    for (int ks = 0; ks < 2; ks++)
      qb[mb][ks] = *(const bf16x8*)&qkv[(tok0 + qblk + mb * 16 + l16) * qrow +
                                        h * HDIM + ks * 32 + quad * 8];

  bf16x8 ones1;
#pragma unroll
  for (int e = 0; e < 8; e++) ones1[e] = (__bf16)1.0f;

  f32x4 l_acc[2];  // ones-MFMA accumulator: every reg/quad = l[q=l16]
  f32x4 o_acc[2][4];  // [mb][db], O^T layout (rows d, cols q)
#pragma unroll
  for (int mb = 0; mb < 2; mb++) {
    l_acc[mb] = (f32x4){0.f, 0.f, 0.f, 0.f};
#pragma unroll
    for (int db = 0; db < 4; db++) o_acc[mb][db] = (f32x4){0.f, 0.f, 0.f, 0.f};
  }

  int srow = lane >> 3;            // 0..7: row within 8-row staging group
  int schunk = (lane & 7) ^ srow;  // swizzled 16B source chunk

  // prologue: stage first tile into buf matching its parity
#pragma unroll
  for (int t = 0; t < 2; t++) {
    int rbase = wave * 16 + t * 8;
    const unsigned short* ga =
        &qkv[(tok0 + kvbase + rbase + srow) * qrow + H + h * HDIM + schunk * 8];
    __builtin_amdgcn_global_load_lds(
        (const __attribute__((address_space(1))) unsigned int*)ga,
        (__attribute__((address_space(3))) unsigned int*)(&Ks[(kvbase >> 6) & 1][rbase * 64]),
        16, 0, 0);
  }

  for (int kv0 = kvbase; kv0 < kvbase + KVLEN; kv0 += 64) {
    int buf = (kv0 >> 6) & 1;
    const unsigned short* Kb = Ks[buf];
    unsigned short* Kn = Ks[buf ^ 1];
    __syncthreads();  // vmcnt(0) drain = Ks[buf] staged; fences Kn readers
    // V A-fragments for this tile — issued BEFORE next-tile stage so the
    // PV-side wait on them leaves the stage outstanding
    bf16x8 va[4][2];
#pragma unroll
    for (int db = 0; db < 4; db++)
#pragma unroll
      for (int ks = 0; ks < 2; ks++)
        va[db][ks] = *(const bf16x8*)&vt[vbase + (size_t)(db * 16 + l16) * SEQ +
                                         kv0 + ks * 32 + quad * 8];
    if (kv0 + 64 < kvbase + KVLEN) {
#pragma unroll
      for (int t = 0; t < 2; t++) {
        int rbase = wave * 16 + t * 8;
        const unsigned short* ga =
            &qkv[(tok0 + kv0 + 64 + rbase + srow) * qrow + H + h * HDIM + schunk * 8];
        __builtin_amdgcn_global_load_lds(
            (const __attribute__((address_space(1))) unsigned int*)ga,
            (__attribute__((address_space(3))) unsigned int*)(Kn + rbase * 64), 16, 0, 0);
      }
    }
    // per 32-kv half: S^T strips -> exp/pack -> partial drain -> PV
#pragma unroll
    for (int half = 0; half < 2; half++) {
#pragma unroll
      for (int nbl = 0; nbl < 2; nbl++) {
        int nb = half * 2 + nbl;
        int row = nb * 16 + l16;
        bf16x8 ka[2];
#pragma unroll
        for (int ks = 0; ks < 2; ks++) {
          int pc = (ks * 4 + quad) ^ (row & 7);
          ka[ks] = *(const bf16x8*)&Kb[row * 64 + pc * 8];
        }
        f32x4 st[2];
#pragma unroll
        for (int mb = 0; mb < 2; mb++) st[mb] = (f32x4){0.f, 0.f, 0.f, 0.f};
        __builtin_amdgcn_s_setprio(1);
#pragma unroll
        for (int ks = 0; ks < 2; ks++)
#pragma unroll
          for (int mb = 0; mb < 2; mb++)
            st[mb] = __builtin_amdgcn_mfma_f32_16x16x32_bf16(ka[ks], qb[mb][ks], st[mb], 0, 0, 0);
        __builtin_amdgcn_s_setprio(0);
#pragma unroll
        for (int mb = 0; mb < 2; mb++) {
          // Q was pre-scaled by 0.125*log2(e): P = 2^st, bare v_exp_f32.
          float p0, p1, p2, p3;
          asm("v_exp_f32 %0, %1" : "=v"(p0) : "v"(st[mb][0]));
          asm("v_exp_f32 %0, %1" : "=v"(p1) : "v"(st[mb][1]));
          asm("v_exp_f32 %0, %1" : "=v"(p2) : "v"(st[mb][2]));
          asm("v_exp_f32 %0, %1" : "=v"(p3) : "v"(st[mb][3]));
          bf16x4 pk = {(__bf16)p0, (__bf16)p1, (__bf16)p2, (__bf16)p3};
          *(bf16x4*)&Psw[(mb * 16 + l16) * LPs + nb * 16 + quad * 4] = pk;
        }
      }
      // drain our wave's Ps writes for this half (wave-private, no barrier)
      __asm__ volatile("s_waitcnt lgkmcnt(0)" ::: "memory");
      bf16x8 pb[2];
#pragma unroll
      for (int mb = 0; mb < 2; mb++)
        pb[mb] = *(const bf16x8*)&Psw[(mb * 16 + l16) * LPs + half * 32 + quad * 8];
      __builtin_amdgcn_s_setprio(1);
#pragma unroll
      for (int db = 0; db < 4; db++)
#pragma unroll
        for (int mb = 0; mb < 2; mb++)
          o_acc[mb][db] = __builtin_amdgcn_mfma_f32_16x16x32_bf16(va[db][half], pb[mb],
                                                                  o_acc[mb][db], 0, 0, 0);
      // l-row: sum_k P[k][q] accumulated on the matrix pipe (replaces VALU adds)
#pragma unroll
      for (int mb = 0; mb < 2; mb++)
        l_acc[mb] = __builtin_amdgcn_mfma_f32_16x16x32_bf16(ones1, pb[mb], l_acc[mb], 0, 0, 0);
      __builtin_amdgcn_s_setprio(0);
    }
  }
  if (NSPLIT == 2) {
    // unnormalized f32 partials; per (mb,db) store: 4 quads x 16B = 64B/row
#pragma unroll
    for (int mb = 0; mb < 2; mb++) {
      int q = qblk + mb * 16 + l16;
      size_t rowo = ((size_t)sp * NTOK + tok0 + q) * H + h * HDIM;
#pragma unroll
      for (int db = 0; db < 4; db++)
        *(f32x4*)&opart[rowo + db * 16 + quad * 4] = o_acc[mb][db];
      if (quad == 0) lsum[((size_t)sp * (BATCH * NHEAD) + bh) * SEQ + q] = l_acc[mb][0];
    }
  } else {
    // O^T C-layout: col q = mb*16+l16, rows d = db*16+quad*4+r -> 8B stores
#pragma unroll
    for (int mb = 0; mb < 2; mb++) {
      float inv = 1.0f / l_acc[mb][0];
#pragma unroll
      for (int db = 0; db < 4; db++) {
        ushort4v o;
#pragma unroll
        for (int r = 0; r < 4; r++) o[r] = f2bf(o_acc[mb][db][r] * inv);
        *(ushort4v*)&attn_out[(tok0 + qblk + mb * 16 + l16) * H + h * HDIM +
                              db * 16 + quad * 4] = o;
      }
    }
  }
}

// ---------- combine: attn = (O0 + O1) / (l0 + l1), f32 -> bf16 ----------
__global__ __launch_bounds__(256)
void attn_combine_kernel(const float* __restrict__ opart,
                         const float* __restrict__ lsum,
                         unsigned short* __restrict__ attn_out) {
  int tok = blockIdx.x;
  int t = threadIdx.x;
  int d4 = t * 4;
  int hh = d4 >> 6;
  int b = tok >> 11;
  int bh = b * NHEAD + hh;
  int qs = tok & (SEQ - 1);
  float l0 = lsum[(size_t)bh * SEQ + qs];
  float l1 = lsum[((size_t)BATCH * NHEAD + bh) * SEQ + qs];
  float inv = 1.0f / (l0 + l1);
  float4 a = *(const float4*)&opart[(size_t)tok * H + d4];
  float4 c = *(const float4*)&opart[((size_t)NTOK + tok) * H + d4];
  ushort4v o;
  o[0] = f2bf((a.x + c.x) * inv);
  o[1] = f2bf((a.y + c.y) * inv);
  o[2] = f2bf((a.z + c.z) * inv);
  o[3] = f2bf((a.w + c.w) * inv);
  *(ushort4v*)&attn_out[(size_t)tok * H + d4] = o;
}

extern "C" void kernel_launch(void* const* d_in, const int* in_sizes, int n_in,
                              void* d_out, int out_size, void* d_ws, size_t ws_size,
                              hipStream_t stream) {
  const float* x = (const float*)d_in[0];
  const float* ln1_g = (const float*)d_in[1];
  const float* ln1_b = (const float*)d_in[2];
  const float* qkv_w = (const float*)d_in[3];
  const float* qkv_b = (const float*)d_in[4];
  const float* out_w = (const float*)d_in[5];
  const float* out_b = (const float*)d_in[6];
  const float* ln2_g = (const float*)d_in[7];
  const float* ln2_b = (const float*)d_in[8];
  const float* w1 = (const float*)d_in[9];
  const float* b1 = (const float*)d_in[10];
  const float* w2 = (const float*)d_in[11];
  const float* b2 = (const float*)d_in[12];
  float* outp = (float*)d_out;

  size_t off = 0;
  auto take = [&](size_t n) {
    char* p = (char*)d_ws + off;
    off += (n + 255) & ~(size_t)255;
    return p;
  };
  unsigned short* h1 = (unsigned short*)take((size_t)NTOK * H * 2);       // also h2
  unsigned short* qkvb = (unsigned short*)take((size_t)NTOK * 3 * H * 2); // qkv; later mid
  unsigned short* attn = (unsigned short*)take((size_t)NTOK * H * 2);
  float* x1 = (float*)take((size_t)NTOK * H * 4);
  unsigned short* qkvwt = (unsigned short*)take((size_t)3 * H * H * 2);
  unsigned short* outwt = (unsigned short*)take((size_t)H * H * 2);
  unsigned short* w1t = (unsigned short*)take((size_t)H * IDIM * 2);
  unsigned short* w2t = (unsigned short*)take((size_t)H * IDIM * 2);
  float* opart = (float*)take((size_t)2 * NTOK * H * 4);                  // 64MB (split-KV)
  float* lsum = (float*)take((size_t)2 * BATCH * NHEAD * SEQ * 4);        // 1MB
  bool use_split = off <= ws_size;
  unsigned short* h2 = h1;
  unsigned short* mid = qkvb;                // [NTOK][IDIM] aliases qkv+attn exactly
  unsigned short* vt = (unsigned short*)x1;  // vt dead before proj writes x1

  dim3 tb(32, 8);
  transpose_cast_kernel<<<dim3(3 * H / 32, H / 32), tb, 0, stream>>>(qkv_w, qkvwt, H, 3 * H);
  transpose_cast_kernel<<<dim3(H / 32, H / 32), tb, 0, stream>>>(out_w, outwt, H, H);
  transpose_cast_kernel<<<dim3(IDIM / 32, H / 32), tb, 0, stream>>>(w1, w1t, H, IDIM);
  transpose_cast_kernel<<<dim3(H / 32, IDIM / 32), tb, 0, stream>>>(w2, w2t, IDIM, H);

  layernorm_kernel<<<NTOK, 256, 0, stream>>>(x, ln1_g, ln1_b, h1);
  // QKV GEMM; v-slice blocks (n0>=2H) write vt transposed directly
  gemm_bt_kernel<0><<<dim3(3 * H / 128, NTOK / 128), 256, 0, stream>>>(
      h1, qkvwt, qkv_b, nullptr, qkvb, vt, NTOK, 3 * H, H);
  if (use_split) {
    flash_attn_kernel<2><<<dim3(SEQ / 128 * BATCH * NHEAD * 2), 256, 0, stream>>>(
        qkvb, vt, attn, opart, lsum);
    attn_combine_kernel<<<dim3(NTOK), 256, 0, stream>>>(opart, lsum, attn);
  } else {
    flash_attn_kernel<1><<<dim3(SEQ / 128 * BATCH * NHEAD), 256, 0, stream>>>(
        qkvb, vt, attn, nullptr, nullptr);
  }
  gemm_bt_kernel<2><<<dim3(H / 128, NTOK / 128), 256, 0, stream>>>(
      attn, outwt, out_b, x, x1, nullptr, NTOK, H, H);
  layernorm_kernel<<<NTOK, 256, 0, stream>>>(x1, ln2_g, ln2_b, h2);
  gemm_bt_kernel<1><<<dim3(IDIM / 128, NTOK / 128), 256, 0, stream>>>(
      h2, w1t, b1, nullptr, mid, nullptr, NTOK, IDIM, H);
  gemm_bt_kernel<2><<<dim3(H / 128, NTOK / 128), 256, 0, stream>>>(
      mid, w2t, b2, x1, outp, nullptr, NTOK, H, IDIM);
}

// Round 3
// 611.285 us; speedup vs baseline: 1.0376x; 1.0207x over previous
//
#include <hip/hip_runtime.h>
#include <math.h>

#define H 1024
#define NHEAD 16
#define HDIM 64
#define IDIM 4096
#define BATCH 4
#define SEQ 2048
#define NTOK 8192
#define LN_EPS 1e-5f

// 0.125 * log2(e): folded into Q at QKV-GEMM epilogue so attention's softmax
// is a raw v_exp_f32 (2^x) with zero preceding VALU muls.
#define QK_EXP2_SCALE 0.18033688011112042f

typedef __bf16 bf16x8 __attribute__((ext_vector_type(8)));
typedef __bf16 bf16x4 __attribute__((ext_vector_type(4)));
typedef float f32x4 __attribute__((ext_vector_type(4)));
typedef unsigned short ushort8 __attribute__((ext_vector_type(8)));
typedef unsigned short ushort4v __attribute__((ext_vector_type(4)));

__device__ __forceinline__ unsigned short f2bf(float f) {
  union { float f; unsigned int u; } v; v.f = f;
  unsigned int u = v.u;
  return (unsigned short)((u + 0x7FFFu + ((u >> 16) & 1u)) >> 16);
}

// ---------- transpose + cast: W[K][N] f32 -> Wt[N][K] bf16 ----------
__global__ void transpose_cast_kernel(const float* __restrict__ W,
                                      unsigned short* __restrict__ Wt,
                                      int K, int N) {
  __shared__ unsigned short tile[32][33];
  int n0 = blockIdx.x * 32, k0 = blockIdx.y * 32;
  int tx = threadIdx.x, ty = threadIdx.y;  // 32 x 8
#pragma unroll
  for (int i = 0; i < 4; i++) {
    int k = ty + i * 8;
    tile[tx][k] = f2bf(W[(size_t)(k0 + k) * N + n0 + tx]);
  }
  __syncthreads();
#pragma unroll
  for (int i = 0; i < 4; i++) {
    int n = ty + i * 8;
    Wt[(size_t)(n0 + n) * K + k0 + tx] = tile[n][tx];
  }
}

// ---------- layernorm: f32 [rows][H] -> bf16 ----------
__global__ __launch_bounds__(256)
void layernorm_kernel(const float* __restrict__ x, const float* __restrict__ g,
                      const float* __restrict__ b, unsigned short* __restrict__ out) {
  __shared__ float sb[4];
  int row = blockIdx.x;
  int tid = threadIdx.x;
  const float4* xr = (const float4*)(x + (size_t)row * H);
  float4 v = xr[tid];
  float s = v.x + v.y + v.z + v.w;
#pragma unroll
  for (int o = 32; o > 0; o >>= 1) s += __shfl_down(s, o);
  if ((tid & 63) == 0) sb[tid >> 6] = s;
  __syncthreads();
  float mu = (sb[0] + sb[1] + sb[2] + sb[3]) * (1.0f / H);
  __syncthreads();
  float dx = v.x - mu, dy = v.y - mu, dz = v.z - mu, dw = v.w - mu;
  float s2 = dx * dx + dy * dy + dz * dz + dw * dw;
#pragma unroll
  for (int o = 32; o > 0; o >>= 1) s2 += __shfl_down(s2, o);
  if ((tid & 63) == 0) sb[tid >> 6] = s2;
  __syncthreads();
  float var = (sb[0] + sb[1] + sb[2] + sb[3]) * (1.0f / H);
  float rs = rsqrtf(var + LN_EPS);
  float4 gv = ((const float4*)g)[tid];
  float4 bv = ((const float4*)b)[tid];
  ushort4v ov;
  ov[0] = f2bf(dx * rs * gv.x + bv.x);
  ov[1] = f2bf(dy * rs * gv.y + bv.y);
  ov[2] = f2bf(dz * rs * gv.z + bv.z);
  ov[3] = f2bf(dw * rs * gv.w + bv.w);
  ((ushort4v*)(out + (size_t)row * H))[tid] = ov;
}

// ---------- GEMM: C = A(bf16,[M][K]) @ Bt(bf16,[N][K])^T + bias ----------
// Single-barrier double-buffered K-loop: tile k+1's global_load_lds issued
// right after the barrier that publishes tile k; the NEXT iteration's barrier
// (implicit vmcnt(0) drain) is the wait -> staging gets a full compute phase
// in flight, and barrier count halves vs the 2-barrier m97 structure.
// MFMA computes C^T (lane owns row m=l16, reg r = 4 consecutive N cols).
// EPI 0: bf16 (q-slice pre-scaled by QK_EXP2_SCALE; opt fused V-transpose for
// QKV v-slice); 1: bf16 gelu; 2: f32+res.
template <int EPI>
__global__ __launch_bounds__(256)
void gemm_bt_kernel(const unsigned short* __restrict__ A,
                    const unsigned short* __restrict__ Bt,
                    const float* __restrict__ bias,
                    const float* __restrict__ res,
                    void* __restrict__ out, unsigned short* __restrict__ vt_out,
                    int M, int N, int K) {
  __shared__ __align__(16) unsigned short As[2][128 * 32];
  __shared__ __align__(16) unsigned short Bs[2][128 * 32];
  int tid = threadIdx.x;
  int wave = tid >> 6, lane = tid & 63;
  int quad = lane >> 4, l16 = lane & 15;
  int wm = wave >> 1, wn = wave & 1;
  int m0 = blockIdx.y * 128, n0 = blockIdx.x * 128;
  f32x4 acc[4][4];  // [i=m strip][j=n strip]; reg r = n offset (C^T layout)
#pragma unroll
  for (int i = 0; i < 4; i++)
#pragma unroll
    for (int j = 0; j < 4; j++) acc[i][j] = (f32x4){0.f, 0.f, 0.f, 0.f};

  int rl = (lane >> 2);
  int cphys = lane & 3;

  auto stage = [&](int k0, int sel) {
#pragma unroll
    for (int t = 0; t < 2; t++) {
      int ch = wave * 2 + t;
      int rloc = ch * 16 + rl;
      int clog = cphys ^ ((rloc >> 1) & 3);
      const unsigned short* ga = A + (size_t)(m0 + rloc) * K + k0 + clog * 8;
      __builtin_amdgcn_global_load_lds(
          (const __attribute__((address_space(1))) unsigned int*)ga,
          (__attribute__((address_space(3))) unsigned int*)(&As[sel][ch * 512]), 16, 0, 0);
      const unsigned short* gb = Bt + (size_t)(n0 + rloc) * K + k0 + clog * 8;
      __builtin_amdgcn_global_load_lds(
          (const __attribute__((address_space(1))) unsigned int*)gb,
          (__attribute__((address_space(3))) unsigned int*)(&Bs[sel][ch * 512]), 16, 0, 0);
    }
  };

  stage(0, 0);  // prologue
  for (int k0 = 0; k0 < K; k0 += 32) {
    int sel = (k0 >> 5) & 1;
    // single barrier: vmcnt(0) drain = wait for tile k0's staging (issued one
    // full iteration ago); lgkm drain = all waves done reading buf sel^1.
    __syncthreads();
    if (k0 + 32 < K) stage(k0 + 32, sel ^ 1);
    bf16x8 af[4], bfv[4];
#pragma unroll
    for (int i = 0; i < 4; i++) {
      int ra = wm * 64 + i * 16 + l16;
      af[i] = *(const bf16x8*)&As[sel][ra * 32 + ((quad ^ ((ra >> 1) & 3)) << 3)];
      int rb = wn * 64 + i * 16 + l16;
      bfv[i] = *(const bf16x8*)&Bs[sel][rb * 32 + ((quad ^ ((rb >> 1) & 3)) << 3)];
    }
#pragma unroll
    for (int i = 0; i < 4; i++)
#pragma unroll
      for (int j = 0; j < 4; j++)
        acc[i][j] = __builtin_amdgcn_mfma_f32_16x16x32_bf16(bfv[j], af[i], acc[i][j], 0, 0, 0);
  }
  // epilogue: lane = row m (l16), reg r = col n offset (quad*4+r)
  bool vslice = (EPI == 0) && (vt_out != nullptr) && (n0 >= 2 * H);
#pragma unroll
  for (int i = 0; i < 4; i++) {
    int m = m0 + wm * 64 + i * 16 + l16;
#pragma unroll
    for (int j = 0; j < 4; j++) {
      int nb = n0 + wn * 64 + j * 16 + quad * 4;
      float4 bv4 = *(const float4*)&bias[nb];
      float v0 = acc[i][j][0] + bv4.x;
      float v1 = acc[i][j][1] + bv4.y;
      float v2 = acc[i][j][2] + bv4.z;
      float v3 = acc[i][j][3] + bv4.w;
      size_t off = (size_t)m * N + nb;
      if (EPI == 0) {
        if (vslice) {
          // write vt[bh][d][s] transposed; skip the qkvb row write
          int bb = m >> 11, s = m & (SEQ - 1);
          int cb = nb - 2 * H;
          int hh = cb >> 6, dd = cb & 63;
          size_t base = ((size_t)(bb * NHEAD + hh) * HDIM + dd) * SEQ + s;
          vt_out[base] = f2bf(v0);
          vt_out[base + SEQ] = f2bf(v1);
          vt_out[base + 2 * SEQ] = f2bf(v2);
          vt_out[base + 3 * SEQ] = f2bf(v3);
        } else {
          // q-slice (n0 < H): fold softmax scale * log2(e) into Q so the
          // attention kernel's exp is a bare v_exp_f32 (saves 2 muls/elem).
          if (n0 < H) {
            v0 *= QK_EXP2_SCALE; v1 *= QK_EXP2_SCALE;
            v2 *= QK_EXP2_SCALE; v3 *= QK_EXP2_SCALE;
          }
          bf16x4 pk = {(__bf16)v0, (__bf16)v1, (__bf16)v2, (__bf16)v3};
          *(bf16x4*)&((unsigned short*)out)[off] = pk;
        }
      } else if (EPI == 1) {
        float g0 = v0 / (1.f + __expf(-1.5957691216057308f * (v0 + 0.044715f * v0 * v0 * v0)));
        float g1 = v1 / (1.f + __expf(-1.5957691216057308f * (v1 + 0.044715f * v1 * v1 * v1)));
        float g2 = v2 / (1.f + __expf(-1.5957691216057308f * (v2 + 0.044715f * v2 * v2 * v2)));
        float g3 = v3 / (1.f + __expf(-1.5957691216057308f * (v3 + 0.044715f * v3 * v3 * v3)));
        bf16x4 pk = {(__bf16)g0, (__bf16)g1, (__bf16)g2, (__bf16)g3};
        *(bf16x4*)&((unsigned short*)out)[off] = pk;
      } else {
        float4 rv = *(const float4*)&res[off];
        float4 o4;
        o4.x = v0 + rv.x; o4.y = v1 + rv.y; o4.z = v2 + rv.z; o4.w = v3 + rv.w;
        *(float4*)&((float*)out)[off] = o4;
      }
    }
  }
}

// ---------- flash attention v10: 8-wave blocks for TLP ----------
// R2 post-mortem: residency capped at ~3 blocks/CU regardless of grid size
// (occ 30-35% both rounds) -> grid-side splitting can't add waves. Fix the
// cap's denominator instead: 8-wave blocks (512 thr, BQ=256, wave owns 32 q)
// put 16 waves/CU at only 2 blocks/CU (LDS 36.9KB x2 = 74KB of 160; grid 512
// = exactly 2/CU, perfectly balanced). __launch_bounds__(512,4) pins the
// register budget to <=128 so 2 blocks always fit the unified VGPR file.
// Register diet funding it: va per-32kv-half (16 regs, reload after PV of
// half 0 hides under QK+exp of half 1); l back to 2 VALU scalars + end shfl.
// Split-KV + combine removed (R2: pure overhead).
// Kept from R1/R2: XCD-bh swizzle (512 = 8 XCD x 64: XCD j owns heads
// [j*8,j*8+8) -> K/V L2-resident, FETCH 139->24MB), exp2-prescaled Q (bare
// v_exp_f32), setprio around MFMA clusters, Ks double-buffer with single
// barrier per iter (implicit vmcnt(0) = wait for stage issued last iter),
// Ps LPs=40 wave-private with lgkm-only drains.
__global__ __launch_bounds__(512, 4)
void flash_attn_kernel(const unsigned short* __restrict__ qkv,
                       const unsigned short* __restrict__ vt,
                       unsigned short* __restrict__ attn_out) {
  constexpr int LPs = 40;
  __shared__ __align__(16) unsigned short Ks[2][64 * 64];
  __shared__ __align__(16) unsigned short Ps[8 * 32 * LPs];
  int tid = threadIdx.x;
  int wave = tid >> 6, lane = tid & 63;
  int quad = lane >> 4, l16 = lane & 15;
  int d = blockIdx.x;
  int logical = (d & 7) * 64 + (d >> 3);  // XCD-bh grouping (bijective, 512=8*64)
  int bh = logical >> 3, qi = logical & 7;
  int b = bh >> 4, h = bh & 15;
  int qblk = qi * 256 + wave * 32;
  const size_t qrow = 3 * H;
  const size_t tok0 = (size_t)b * SEQ;
  const size_t vbase = (size_t)bh * HDIM * SEQ;
  unsigned short* Psw = Ps + wave * 32 * LPs;

  // Q B-fragments (q on l16), register-resident for the whole loop
  bf16x8 qb[2][2];
#pragma unroll
  for (int mb = 0; mb < 2; mb++)
#pragma unroll
    for (int ks = 0; ks < 2; ks++)
      qb[mb][ks] = *(const bf16x8*)&qkv[(tok0 + qblk + mb * 16 + l16) * qrow +
                                        h * HDIM + ks * 32 + quad * 8];

  float l_part[2] = {0.f, 0.f};
  f32x4 o_acc[2][4];  // [mb][db], O^T layout (rows d, cols q)
#pragma unroll
  for (int mb = 0; mb < 2; mb++)
#pragma unroll
    for (int db = 0; db < 4; db++) o_acc[mb][db] = (f32x4){0.f, 0.f, 0.f, 0.f};

  int srow = lane >> 3;            // 0..7: row within 8-row staging group
  int schunk = (lane & 7) ^ srow;  // swizzled 16B source chunk

  // prologue: stage tile 0 into buf 0 (wave stages rows [wave*8, wave*8+8))
  {
    const unsigned short* ga =
        &qkv[(tok0 + wave * 8 + srow) * qrow + H + h * HDIM + schunk * 8];
    __builtin_amdgcn_global_load_lds(
        (const __attribute__((address_space(1))) unsigned int*)ga,
        (__attribute__((address_space(3))) unsigned int*)(&Ks[0][wave * 8 * 64]), 16, 0, 0);
  }

  for (int kv0 = 0; kv0 < SEQ; kv0 += 64) {
    int buf = (kv0 >> 6) & 1;
    const unsigned short* Kb = Ks[buf];
    unsigned short* Kn = Ks[buf ^ 1];
    __syncthreads();  // vmcnt(0) drain = Ks[buf] staged; fences Kn readers
    // V A-fragments for half 0 only (16 regs); half 1 reloads after PV0
    bf16x8 va[4];
#pragma unroll
    for (int db = 0; db < 4; db++)
      va[db] = *(const bf16x8*)&vt[vbase + (size_t)(db * 16 + l16) * SEQ +
                                   kv0 + quad * 8];
    if (kv0 + 64 < SEQ) {
      const unsigned short* ga =
          &qkv[(tok0 + kv0 + 64 + wave * 8 + srow) * qrow + H + h * HDIM + schunk * 8];
      __builtin_amdgcn_global_load_lds(
          (const __attribute__((address_space(1))) unsigned int*)ga,
          (__attribute__((address_space(3))) unsigned int*)(Kn + wave * 8 * 64), 16, 0, 0);
    }
    // per 32-kv half: S^T strips -> exp/pack -> partial drain -> PV
#pragma unroll
    for (int half = 0; half < 2; half++) {
#pragma unroll
      for (int nbl = 0; nbl < 2; nbl++) {
        int nb = half * 2 + nbl;
        int row = nb * 16 + l16;
        bf16x8 ka[2];
#pragma unroll
        for (int ks = 0; ks < 2; ks++) {
          int pc = (ks * 4 + quad) ^ (row & 7);
          ka[ks] = *(const bf16x8*)&Kb[row * 64 + pc * 8];
        }
        f32x4 st[2];
#pragma unroll
        for (int mb = 0; mb < 2; mb++) st[mb] = (f32x4){0.f, 0.f, 0.f, 0.f};
        __builtin_amdgcn_s_setprio(1);
#pragma unroll
        for (int ks = 0; ks < 2; ks++)
#pragma unroll
          for (int mb = 0; mb < 2; mb++)
            st[mb] = __builtin_amdgcn_mfma_f32_16x16x32_bf16(ka[ks], qb[mb][ks], st[mb], 0, 0, 0);
        __builtin_amdgcn_s_setprio(0);
#pragma unroll
        for (int mb = 0; mb < 2; mb++) {
          // Q was pre-scaled by 0.125*log2(e): P = 2^st, bare v_exp_f32.
          float p0, p1, p2, p3;
          asm("v_exp_f32 %0, %1" : "=v"(p0) : "v"(st[mb][0]));
          asm("v_exp_f32 %0, %1" : "=v"(p1) : "v"(st[mb][1]));
          asm("v_exp_f32 %0, %1" : "=v"(p2) : "v"(st[mb][2]));
          asm("v_exp_f32 %0, %1" : "=v"(p3) : "v"(st[mb][3]));
          l_part[mb] += (p0 + p1) + (p2 + p3);
          bf16x4 pk = {(__bf16)p0, (__bf16)p1, (__bf16)p2, (__bf16)p3};
          *(bf16x4*)&Psw[(mb * 16 + l16) * LPs + nb * 16 + quad * 4] = pk;
        }
      }
      // drain our wave's Ps writes for this half (wave-private, no barrier)
      __asm__ volatile("s_waitcnt lgkmcnt(0)" ::: "memory");
      bf16x8 pb[2];
#pragma unroll
      for (int mb = 0; mb < 2; mb++)
        pb[mb] = *(const bf16x8*)&Psw[(mb * 16 + l16) * LPs + half * 32 + quad * 8];
      __builtin_amdgcn_s_setprio(1);
#pragma unroll
      for (int db = 0; db < 4; db++)
#pragma unroll
        for (int mb = 0; mb < 2; mb++)
          o_acc[mb][db] = __builtin_amdgcn_mfma_f32_16x16x32_bf16(va[db], pb[mb],
                                                                  o_acc[mb][db], 0, 0, 0);
      __builtin_amdgcn_s_setprio(0);
      if (half == 0) {
        // reload va for half 1; latency hides under half 1's QK+exp+Ps phase
#pragma unroll
        for (int db = 0; db < 4; db++)
          va[db] = *(const bf16x8*)&vt[vbase + (size_t)(db * 16 + l16) * SEQ +
                                       kv0 + 32 + quad * 8];
      }
    }
  }
  // reduce l across the 4 quads; lane then holds inv-l for its own q = mb*16+l16
#pragma unroll
  for (int mb = 0; mb < 2; mb++) {
    l_part[mb] += __shfl_xor(l_part[mb], 16);
    l_part[mb] += __shfl_xor(l_part[mb], 32);
    l_part[mb] = 1.0f / l_part[mb];
  }
  // O^T C-layout: col q = mb*16+l16, rows d = db*16+quad*4+r (contig) -> 8B stores
#pragma unroll
  for (int mb = 0; mb < 2; mb++) {
#pragma unroll
    for (int db = 0; db < 4; db++) {
      ushort4v o;
#pragma unroll
      for (int r = 0; r < 4; r++) o[r] = f2bf(o_acc[mb][db][r] * l_part[mb]);
      *(ushort4v*)&attn_out[(tok0 + qblk + mb * 16 + l16) * H + h * HDIM +
                            db * 16 + quad * 4] = o;
    }
  }
}

extern "C" void kernel_launch(void* const* d_in, const int* in_sizes, int n_in,
                              void* d_out, int out_size, void* d_ws, size_t ws_size,
                              hipStream_t stream) {
  const float* x = (const float*)d_in[0];
  const float* ln1_g = (const float*)d_in[1];
  const float* ln1_b = (const float*)d_in[2];
  const float* qkv_w = (const float*)d_in[3];
  const float* qkv_b = (const float*)d_in[4];
  const float* out_w = (const float*)d_in[5];
  const float* out_b = (const float*)d_in[6];
  const float* ln2_g = (const float*)d_in[7];
  const float* ln2_b = (const float*)d_in[8];
  const float* w1 = (const float*)d_in[9];
  const float* b1 = (const float*)d_in[10];
  const float* w2 = (const float*)d_in[11];
  const float* b2 = (const float*)d_in[12];
  float* outp = (float*)d_out;

  size_t off = 0;
  auto take = [&](size_t n) {
    char* p = (char*)d_ws + off;
    off += (n + 255) & ~(size_t)255;
    return p;
  };
  unsigned short* h1 = (unsigned short*)take((size_t)NTOK * H * 2);       // also h2
  unsigned short* qkvb = (unsigned short*)take((size_t)NTOK * 3 * H * 2); // qkv; later mid
  unsigned short* attn = (unsigned short*)take((size_t)NTOK * H * 2);
  float* x1 = (float*)take((size_t)NTOK * H * 4);
  unsigned short* qkvwt = (unsigned short*)take((size_t)3 * H * H * 2);
  unsigned short* outwt = (unsigned short*)take((size_t)H * H * 2);
  unsigned short* w1t = (unsigned short*)take((size_t)H * IDIM * 2);
  unsigned short* w2t = (unsigned short*)take((size_t)H * IDIM * 2);
  unsigned short* h2 = h1;
  unsigned short* mid = qkvb;                // [NTOK][IDIM] aliases qkv+attn exactly
  unsigned short* vt = (unsigned short*)x1;  // vt dead before proj writes x1

  dim3 tb(32, 8);
  transpose_cast_kernel<<<dim3(3 * H / 32, H / 32), tb, 0, stream>>>(qkv_w, qkvwt, H, 3 * H);
  transpose_cast_kernel<<<dim3(H / 32, H / 32), tb, 0, stream>>>(out_w, outwt, H, H);
  transpose_cast_kernel<<<dim3(IDIM / 32, H / 32), tb, 0, stream>>>(w1, w1t, H, IDIM);
  transpose_cast_kernel<<<dim3(H / 32, IDIM / 32), tb, 0, stream>>>(w2, w2t, IDIM, H);

  layernorm_kernel<<<NTOK, 256, 0, stream>>>(x, ln1_g, ln1_b, h1);
  // QKV GEMM; v-slice blocks (n0>=2H) write vt transposed directly
  gemm_bt_kernel<0><<<dim3(3 * H / 128, NTOK / 128), 256, 0, stream>>>(
      h1, qkvwt, qkv_b, nullptr, qkvb, vt, NTOK, 3 * H, H);
  // 512 blocks x 512 threads: 8-wave blocks, BQ=256, 2 blocks/CU
  flash_attn_kernel<<<dim3(SEQ / 256 * BATCH * NHEAD), 512, 0, stream>>>(qkvb, vt, attn);
  gemm_bt_kernel<2><<<dim3(H / 128, NTOK / 128), 256, 0, stream>>>(
      attn, outwt, out_b, x, x1, nullptr, NTOK, H, H);
  layernorm_kernel<<<NTOK, 256, 0, stream>>>(x1, ln2_g, ln2_b, h2);
  gemm_bt_kernel<1><<<dim3(IDIM / 128, NTOK / 128), 256, 0, stream>>>(
      h2, w1t, b1, nullptr, mid, nullptr, NTOK, IDIM, H);
  gemm_bt_kernel<2><<<dim3(H / 128, NTOK / 128), 256, 0, stream>>>(
      mid, w2t, b2, x1, outp, nullptr, NTOK, H, IDIM);
}

// Round 5
// 607.913 us; speedup vs baseline: 1.0434x; 1.0055x over previous
//
#include <hip/hip_runtime.h>
#include <math.h>

#define H 1024
#define NHEAD 16
#define HDIM 64
#define IDIM 4096
#define BATCH 4
#define SEQ 2048
#define NTOK 8192
#define LN_EPS 1e-5f

// 0.125 * log2(e): folded into Q at QKV-GEMM epilogue so attention's softmax
// is a raw v_exp_f32 (2^x) with zero preceding VALU muls.
#define QK_EXP2_SCALE 0.18033688011112042f

typedef __bf16 bf16x8 __attribute__((ext_vector_type(8)));
typedef __bf16 bf16x4 __attribute__((ext_vector_type(4)));
typedef float f32x4 __attribute__((ext_vector_type(4)));
typedef unsigned short ushort8 __attribute__((ext_vector_type(8)));
typedef unsigned short ushort4v __attribute__((ext_vector_type(4)));

__device__ __forceinline__ unsigned short f2bf(float f) {
  union { float f; unsigned int u; } v; v.f = f;
  unsigned int u = v.u;
  return (unsigned short)((u + 0x7FFFu + ((u >> 16) & 1u)) >> 16);
}

// ---------- transpose + cast: W[K][N] f32 -> Wt[N][K] bf16 ----------
__global__ void transpose_cast_kernel(const float* __restrict__ W,
                                      unsigned short* __restrict__ Wt,
                                      int K, int N) {
  __shared__ unsigned short tile[32][33];
  int n0 = blockIdx.x * 32, k0 = blockIdx.y * 32;
  int tx = threadIdx.x, ty = threadIdx.y;  // 32 x 8
#pragma unroll
  for (int i = 0; i < 4; i++) {
    int k = ty + i * 8;
    tile[tx][k] = f2bf(W[(size_t)(k0 + k) * N + n0 + tx]);
  }
  __syncthreads();
#pragma unroll
  for (int i = 0; i < 4; i++) {
    int n = ty + i * 8;
    Wt[(size_t)(n0 + n) * K + k0 + tx] = tile[n][tx];
  }
}

// ---------- layernorm: f32 [rows][H] -> bf16 ----------
__global__ __launch_bounds__(256)
void layernorm_kernel(const float* __restrict__ x, const float* __restrict__ g,
                      const float* __restrict__ b, unsigned short* __restrict__ out) {
  __shared__ float sb[4];
  int row = blockIdx.x;
  int tid = threadIdx.x;
  const float4* xr = (const float4*)(x + (size_t)row * H);
  float4 v = xr[tid];
  float s = v.x + v.y + v.z + v.w;
#pragma unroll
  for (int o = 32; o > 0; o >>= 1) s += __shfl_down(s, o);
  if ((tid & 63) == 0) sb[tid >> 6] = s;
  __syncthreads();
  float mu = (sb[0] + sb[1] + sb[2] + sb[3]) * (1.0f / H);
  __syncthreads();
  float dx = v.x - mu, dy = v.y - mu, dz = v.z - mu, dw = v.w - mu;
  float s2 = dx * dx + dy * dy + dz * dz + dw * dw;
#pragma unroll
  for (int o = 32; o > 0; o >>= 1) s2 += __shfl_down(s2, o);
  if ((tid & 63) == 0) sb[tid >> 6] = s2;
  __syncthreads();
  float var = (sb[0] + sb[1] + sb[2] + sb[3]) * (1.0f / H);
  float rs = rsqrtf(var + LN_EPS);
  float4 gv = ((const float4*)g)[tid];
  float4 bv = ((const float4*)b)[tid];
  ushort4v ov;
  ov[0] = f2bf(dx * rs * gv.x + bv.x);
  ov[1] = f2bf(dy * rs * gv.y + bv.y);
  ov[2] = f2bf(dz * rs * gv.z + bv.z);
  ov[3] = f2bf(dw * rs * gv.w + bv.w);
  ((ushort4v*)(out + (size_t)row * H))[tid] = ov;
}

// ---------- GEMM 128^2 (proven single-barrier structure) ----------
// Kept for proj and MLP2 (N=1024: 256^2 tiles would give only 128 blocks =
// half the CUs idle). EPI 2 only: f32 out + residual.
template <int EPI>
__global__ __launch_bounds__(256)
void gemm_bt_kernel(const unsigned short* __restrict__ A,
                    const unsigned short* __restrict__ Bt,
                    const float* __restrict__ bias,
                    const float* __restrict__ res,
                    void* __restrict__ out, unsigned short* __restrict__ vt_out,
                    int M, int N, int K) {
  __shared__ __align__(16) unsigned short As[2][128 * 32];
  __shared__ __align__(16) unsigned short Bs[2][128 * 32];
  int tid = threadIdx.x;
  int wave = tid >> 6, lane = tid & 63;
  int quad = lane >> 4, l16 = lane & 15;
  int wm = wave >> 1, wn = wave & 1;
  int m0 = blockIdx.y * 128, n0 = blockIdx.x * 128;
  f32x4 acc[4][4];
#pragma unroll
  for (int i = 0; i < 4; i++)
#pragma unroll
    for (int j = 0; j < 4; j++) acc[i][j] = (f32x4){0.f, 0.f, 0.f, 0.f};

  int rl = (lane >> 2);
  int cphys = lane & 3;

  auto stage = [&](int k0, int sel) {
#pragma unroll
    for (int t = 0; t < 2; t++) {
      int ch = wave * 2 + t;
      int rloc = ch * 16 + rl;
      int clog = cphys ^ ((rloc >> 1) & 3);
      const unsigned short* ga = A + (size_t)(m0 + rloc) * K + k0 + clog * 8;
      __builtin_amdgcn_global_load_lds(
          (const __attribute__((address_space(1))) unsigned int*)ga,
          (__attribute__((address_space(3))) unsigned int*)(&As[sel][ch * 512]), 16, 0, 0);
      const unsigned short* gb = Bt + (size_t)(n0 + rloc) * K + k0 + clog * 8;
      __builtin_amdgcn_global_load_lds(
          (const __attribute__((address_space(1))) unsigned int*)gb,
          (__attribute__((address_space(3))) unsigned int*)(&Bs[sel][ch * 512]), 16, 0, 0);
    }
  };

  stage(0, 0);
  for (int k0 = 0; k0 < K; k0 += 32) {
    int sel = (k0 >> 5) & 1;
    __syncthreads();
    if (k0 + 32 < K) stage(k0 + 32, sel ^ 1);
    bf16x8 af[4], bfv[4];
#pragma unroll
    for (int i = 0; i < 4; i++) {
      int ra = wm * 64 + i * 16 + l16;
      af[i] = *(const bf16x8*)&As[sel][ra * 32 + ((quad ^ ((ra >> 1) & 3)) << 3)];
      int rb = wn * 64 + i * 16 + l16;
      bfv[i] = *(const bf16x8*)&Bs[sel][rb * 32 + ((quad ^ ((rb >> 1) & 3)) << 3)];
    }
#pragma unroll
    for (int i = 0; i < 4; i++)
#pragma unroll
      for (int j = 0; j < 4; j++)
        acc[i][j] = __builtin_amdgcn_mfma_f32_16x16x32_bf16(bfv[j], af[i], acc[i][j], 0, 0, 0);
  }
#pragma unroll
  for (int i = 0; i < 4; i++) {
    int m = m0 + wm * 64 + i * 16 + l16;
#pragma unroll
    for (int j = 0; j < 4; j++) {
      int nb = n0 + wn * 64 + j * 16 + quad * 4;
      float4 bv4 = *(const float4*)&bias[nb];
      float v0 = acc[i][j][0] + bv4.x;
      float v1 = acc[i][j][1] + bv4.y;
      float v2 = acc[i][j][2] + bv4.z;
      float v3 = acc[i][j][3] + bv4.w;
      size_t off = (size_t)m * N + nb;
      float4 rv = *(const float4*)&res[off];
      float4 o4;
      o4.x = v0 + rv.x; o4.y = v1 + rv.y; o4.z = v2 + rv.z; o4.w = v3 + rv.w;
      *(float4*)&((float*)out)[off] = o4;
    }
  }
}

// ---------- GEMM 256^2 8-phase (m201 template, RACE-FIXED ledger) ----------
// BM=BN=256, BK=64, 8 waves (2M x 4N), LDS 128KB, 1 block/CU,
// __launch_bounds__(512,2) -> <=256 VGPR (acc 128 + af 32 + bv 32 + addr).
// R4 post-mortem: SA0(t+2) was staged at P1 but A(t) half-0 (same buffer
// parity, same region) is last ds_read at P2 -> the load could land before
// the read (L2 hit ~200cyc ~ 1 phase) -> tile t+2 data leaked into tile t.
// CORRECTED ledger, derived from last-read phases
//   [A(t): P0,P2 | B(t): P0,P1 | A(t+1): P4,P6 | B(t+1): P4,P5]:
//   P2: SB0(t+2)            (B(t) last read P1)
//   P3: SA0(t+2), SB1(t+2)  (A(t) last read P2)   + vmcnt(6)
//   P4: SA1(t+2)            (parity-t buf; reads now on parity t+1)
//   P6: SB0(t+3), SB1(t+3)  (B(t+1) last read P5)
//   P7: SA0(t+3), SA1(t+3)  (A(t+1) last read P6) + vmcnt(8)
// Every stage now issues strictly AFTER its region's last read completed
// (barrier-separated), so no landing time can race. Within-phase stage and
// ds_read regions verified disjoint in all 8 phases.
// Arrival: vmcnt(6) end-P3 (14 outstanding -> retire tile t+1's 8 loads,
// 3 t+2-stages in flight); vmcnt(8) end-P7 (16 -> retire t+2's 8, 4 t+3-
// stages in flight). Prologue: tiles 0,1 fully staged (8 stages), vmcnt(8).
// Tail: unclamped parity, clamped global k -> count ledger never changes;
// tail writes land only in already-dead regions.
// LDS XOR swizzle both-sides (chunk ^= row&7, 16B chunks): pre-swizzled
// global source + swizzled ds_read (involution) -> <=2-way b128 conflicts.
// MFMA computes C^T (lane l16 = row m, quad*4+r = col n), same as 128^2.
// EPI 0: bf16 out, q-slice prescale, vslice vt transpose. EPI 1: gelu bf16.
template <int EPI>
__global__ __launch_bounds__(512, 2)
void gemm256_kernel(const unsigned short* __restrict__ A,
                    const unsigned short* __restrict__ Bt,
                    const float* __restrict__ bias,
                    void* __restrict__ out, unsigned short* __restrict__ vt_out,
                    int M, int N, int K) {
  __shared__ __align__(16) unsigned short As[2][256 * 64];
  __shared__ __align__(16) unsigned short Bs[2][256 * 64];
  int tid = threadIdx.x;
  int wave = tid >> 6, lane = tid & 63;
  int quad = lane >> 4, l16 = lane & 15;
  int wm = wave >> 2, wn = wave & 3;
  // XCD swizzle, m-fastest: each XCD gets a contiguous swz run -> cycles m
  // tiles under a resident B weight panel (512KB < 4MB L2/XCD).
  int nwg = gridDim.x * gridDim.y;
  int dlin = blockIdx.y * gridDim.x + blockIdx.x;
  int swz = (dlin & 7) * (nwg >> 3) + (dlin >> 3);
  int nm = gridDim.y;  // M/256
  int mt = swz % nm, nt = swz / nm;
  int m0 = mt * 256, n0 = nt * 256;
  int NT = K >> 6;

  const unsigned short* Abase = A + (size_t)m0 * K;
  const unsigned short* Bbase = Bt + (size_t)n0 * K;

  int srow = lane >> 3;            // row within 8-row staging group
  int schunk = (lane & 7) ^ srow;  // pre-swizzled 16B source chunk

  // stage one 128-row half-tile (2 gload_lds/thread, linear LDS dest,
  // swizzled global source). Ledger-stable tail: clamp global k only.
  auto stage = [&](const unsigned short* gbase, unsigned short* lbase, int tile,
                   int half) {
    int kt = tile < NT ? tile : NT - 1;
    int k0 = kt << 6;
    unsigned short* lb = lbase + (size_t)(tile & 1) * (256 * 64);
#pragma unroll
    for (int L = 0; L < 2; L++) {
      int rloc = half * 128 + L * 64 + wave * 8 + srow;
      const unsigned short* g = gbase + (size_t)rloc * K + k0 + schunk * 8;
      __builtin_amdgcn_global_load_lds(
          (const __attribute__((address_space(1))) unsigned int*)g,
          (__attribute__((address_space(3))) unsigned int*)(lb + (size_t)(half * 128 + L * 64 + wave * 8) * 64),
          16, 0, 0);
    }
  };

  f32x4 acc[8][4];
#pragma unroll
  for (int i = 0; i < 8; i++)
#pragma unroll
    for (int j = 0; j < 4; j++) acc[i][j] = (f32x4){0.f, 0.f, 0.f, 0.f};
  bf16x8 af[4][2];  // current qm half: 4 m-frags x 2 k-slices
  bf16x8 bv[4][2];  // all 4 n-frags x 2 k-slices (persistent per tile)

  // prologue: tiles 0 and 1 fully staged; oldest 8 loads = tile 0.
  stage(Abase, (unsigned short*)As, 0, 0);
  stage(Bbase, (unsigned short*)Bs, 0, 0);
  stage(Abase, (unsigned short*)As, 0, 1);
  stage(Bbase, (unsigned short*)Bs, 0, 1);
  stage(Abase, (unsigned short*)As, 1, 0);
  stage(Bbase, (unsigned short*)Bs, 1, 0);
  stage(Abase, (unsigned short*)As, 1, 1);
  stage(Bbase, (unsigned short*)Bs, 1, 1);
  asm volatile("s_waitcnt vmcnt(8)" ::: "memory");
  __builtin_amdgcn_s_barrier();

  for (int it = 0; it < (NT >> 1); it++) {
    int t = it * 2;
#pragma unroll
    for (int P = 0; P < 8; P++) {
      int ct = t + (P >> 2);
      int sel = ct & 1;
      // --- ds_read this phase's operand subtile ---
      if ((P & 3) == 0) {
#pragma unroll
        for (int i = 0; i < 4; i++) {
          int ra = wm * 128 + i * 16 + l16;
#pragma unroll
          for (int ks = 0; ks < 2; ks++)
            af[i][ks] = *(const bf16x8*)&As[sel][ra * 64 + (((ks * 4 + quad) ^ (ra & 7)) << 3)];
        }
#pragma unroll
        for (int j = 0; j < 2; j++) {
          int rb = wn * 64 + j * 16 + l16;
#pragma unroll
          for (int ks = 0; ks < 2; ks++)
            bv[j][ks] = *(const bf16x8*)&Bs[sel][rb * 64 + (((ks * 4 + quad) ^ (rb & 7)) << 3)];
        }
      } else if ((P & 3) == 1) {
#pragma unroll
        for (int j = 0; j < 2; j++) {
          int rb = wn * 64 + (2 + j) * 16 + l16;
#pragma unroll
          for (int ks = 0; ks < 2; ks++)
            bv[2 + j][ks] = *(const bf16x8*)&Bs[sel][rb * 64 + (((ks * 4 + quad) ^ (rb & 7)) << 3)];
        }
      } else if ((P & 3) == 2) {
#pragma unroll
        for (int i = 0; i < 4; i++) {
          int ra = wm * 128 + (4 + i) * 16 + l16;
#pragma unroll
          for (int ks = 0; ks < 2; ks++)
            af[i][ks] = *(const bf16x8*)&As[sel][ra * 64 + (((ks * 4 + quad) ^ (ra & 7)) << 3)];
        }
      }
      // --- stage per the corrected ledger (issue only after last read) ---
      switch (P) {
        case 2: stage(Bbase, (unsigned short*)Bs, t + 2, 0); break;
        case 3: stage(Abase, (unsigned short*)As, t + 2, 0);
                stage(Bbase, (unsigned short*)Bs, t + 2, 1); break;
        case 4: stage(Abase, (unsigned short*)As, t + 2, 1); break;
        case 6: stage(Bbase, (unsigned short*)Bs, t + 3, 0);
                stage(Bbase, (unsigned short*)Bs, t + 3, 1); break;
        case 7: stage(Abase, (unsigned short*)As, t + 3, 0);
                stage(Abase, (unsigned short*)As, t + 3, 1); break;
        default: break;
      }
      __builtin_amdgcn_s_barrier();
      // --- 16 MFMA: quadrant (qm, qj) over K=64 ---
      int qm = (P >> 1) & 1, qj = P & 1;
      __builtin_amdgcn_s_setprio(1);
#pragma unroll
      for (int i = 0; i < 4; i++)
#pragma unroll
        for (int j = 0; j < 2; j++)
#pragma unroll
          for (int ks = 0; ks < 2; ks++)
            acc[qm * 4 + i][qj * 2 + j] = __builtin_amdgcn_mfma_f32_16x16x32_bf16(
                bv[qj * 2 + j][ks], af[i][ks], acc[qm * 4 + i][qj * 2 + j], 0, 0, 0);
      __builtin_amdgcn_s_setprio(0);
      if (P == 3) asm volatile("s_waitcnt vmcnt(6)" ::: "memory");
      if (P == 7) asm volatile("s_waitcnt vmcnt(8)" ::: "memory");
      __builtin_amdgcn_s_barrier();
    }
  }
  asm volatile("s_waitcnt vmcnt(0)" ::: "memory");

  // epilogue (C^T frag layout, identical convention to 128^2 kernel)
  bool vslice = (EPI == 0) && (vt_out != nullptr) && (n0 >= 2 * H);
#pragma unroll
  for (int i = 0; i < 8; i++) {
    int m = m0 + wm * 128 + i * 16 + l16;
#pragma unroll
    for (int j = 0; j < 4; j++) {
      int nb = n0 + wn * 64 + j * 16 + quad * 4;
      float4 bv4 = *(const float4*)&bias[nb];
      float v0 = acc[i][j][0] + bv4.x;
      float v1 = acc[i][j][1] + bv4.y;
      float v2 = acc[i][j][2] + bv4.z;
      float v3 = acc[i][j][3] + bv4.w;
      size_t off = (size_t)m * N + nb;
      if (EPI == 0) {
        if (vslice) {
          int bb = m >> 11, s = m & (SEQ - 1);
          int cb = nb - 2 * H;
          int hh = cb >> 6, dd = cb & 63;
          size_t base = ((size_t)(bb * NHEAD + hh) * HDIM + dd) * SEQ + s;
          vt_out[base] = f2bf(v0);
          vt_out[base + SEQ] = f2bf(v1);
          vt_out[base + 2 * SEQ] = f2bf(v2);
          vt_out[base + 3 * SEQ] = f2bf(v3);
        } else {
          if (n0 < H) {
            v0 *= QK_EXP2_SCALE; v1 *= QK_EXP2_SCALE;
            v2 *= QK_EXP2_SCALE; v3 *= QK_EXP2_SCALE;
          }
          bf16x4 pk = {(__bf16)v0, (__bf16)v1, (__bf16)v2, (__bf16)v3};
          *(bf16x4*)&((unsigned short*)out)[off] = pk;
        }
      } else {
        float g0 = v0 / (1.f + __expf(-1.5957691216057308f * (v0 + 0.044715f * v0 * v0 * v0)));
        float g1 = v1 / (1.f + __expf(-1.5957691216057308f * (v1 + 0.044715f * v1 * v1 * v1)));
        float g2 = v2 / (1.f + __expf(-1.5957691216057308f * (v2 + 0.044715f * v2 * v2 * v2)));
        float g3 = v3 / (1.f + __expf(-1.5957691216057308f * (v3 + 0.044715f * v3 * v3 * v3)));
        bf16x4 pk = {(__bf16)g0, (__bf16)g1, (__bf16)g2, (__bf16)g3};
        *(bf16x4*)&((unsigned short*)out)[off] = pk;
      }
    }
  }
}

// ---------- flash attention v10: 8-wave blocks for TLP (unchanged) ----------
__global__ __launch_bounds__(512, 4)
void flash_attn_kernel(const unsigned short* __restrict__ qkv,
                       const unsigned short* __restrict__ vt,
                       unsigned short* __restrict__ attn_out) {
  constexpr int LPs = 40;
  __shared__ __align__(16) unsigned short Ks[2][64 * 64];
  __shared__ __align__(16) unsigned short Ps[8 * 32 * LPs];
  int tid = threadIdx.x;
  int wave = tid >> 6, lane = tid & 63;
  int quad = lane >> 4, l16 = lane & 15;
  int d = blockIdx.x;
  int logical = (d & 7) * 64 + (d >> 3);  // XCD-bh grouping (bijective, 512=8*64)
  int bh = logical >> 3, qi = logical & 7;
  int b = bh >> 4, h = bh & 15;
  int qblk = qi * 256 + wave * 32;
  const size_t qrow = 3 * H;
  const size_t tok0 = (size_t)b * SEQ;
  const size_t vbase = (size_t)bh * HDIM * SEQ;
  unsigned short* Psw = Ps + wave * 32 * LPs;

  bf16x8 qb[2][2];
#pragma unroll
  for (int mb = 0; mb < 2; mb++)
#pragma unroll
    for (int ks = 0; ks < 2; ks++)
      qb[mb][ks] = *(const bf16x8*)&qkv[(tok0 + qblk + mb * 16 + l16) * qrow +
                                        h * HDIM + ks * 32 + quad * 8];

  float l_part[2] = {0.f, 0.f};
  f32x4 o_acc[2][4];
#pragma unroll
  for (int mb = 0; mb < 2; mb++)
#pragma unroll
    for (int db = 0; db < 4; db++) o_acc[mb][db] = (f32x4){0.f, 0.f, 0.f, 0.f};

  int srow = lane >> 3;
  int schunk = (lane & 7) ^ srow;

  {
    const unsigned short* ga =
        &qkv[(tok0 + wave * 8 + srow) * qrow + H + h * HDIM + schunk * 8];
    __builtin_amdgcn_global_load_lds(
        (const __attribute__((address_space(1))) unsigned int*)ga,
        (__attribute__((address_space(3))) unsigned int*)(&Ks[0][wave * 8 * 64]), 16, 0, 0);
  }

  for (int kv0 = 0; kv0 < SEQ; kv0 += 64) {
    int buf = (kv0 >> 6) & 1;
    const unsigned short* Kb = Ks[buf];
    unsigned short* Kn = Ks[buf ^ 1];
    __syncthreads();
    bf16x8 va[4];
#pragma unroll
    for (int db = 0; db < 4; db++)
      va[db] = *(const bf16x8*)&vt[vbase + (size_t)(db * 16 + l16) * SEQ +
                                   kv0 + quad * 8];
    if (kv0 + 64 < SEQ) {
      const unsigned short* ga =
          &qkv[(tok0 + kv0 + 64 + wave * 8 + srow) * qrow + H + h * HDIM + schunk * 8];
      __builtin_amdgcn_global_load_lds(
          (const __attribute__((address_space(1))) unsigned int*)ga,
          (__attribute__((address_space(3))) unsigned int*)(Kn + wave * 8 * 64), 16, 0, 0);
    }
#pragma unroll
    for (int half = 0; half < 2; half++) {
#pragma unroll
      for (int nbl = 0; nbl < 2; nbl++) {
        int nb = half * 2 + nbl;
        int row = nb * 16 + l16;
        bf16x8 ka[2];
#pragma unroll
        for (int ks = 0; ks < 2; ks++) {
          int pc = (ks * 4 + quad) ^ (row & 7);
          ka[ks] = *(const bf16x8*)&Kb[row * 64 + pc * 8];
        }
        f32x4 st[2];
#pragma unroll
        for (int mb = 0; mb < 2; mb++) st[mb] = (f32x4){0.f, 0.f, 0.f, 0.f};
        __builtin_amdgcn_s_setprio(1);
#pragma unroll
        for (int ks = 0; ks < 2; ks++)
#pragma unroll
          for (int mb = 0; mb < 2; mb++)
            st[mb] = __builtin_amdgcn_mfma_f32_16x16x32_bf16(ka[ks], qb[mb][ks], st[mb], 0, 0, 0);
        __builtin_amdgcn_s_setprio(0);
#pragma unroll
        for (int mb = 0; mb < 2; mb++) {
          float p0, p1, p2, p3;
          asm("v_exp_f32 %0, %1" : "=v"(p0) : "v"(st[mb][0]));
          asm("v_exp_f32 %0, %1" : "=v"(p1) : "v"(st[mb][1]));
          asm("v_exp_f32 %0, %1" : "=v"(p2) : "v"(st[mb][2]));
          asm("v_exp_f32 %0, %1" : "=v"(p3) : "v"(st[mb][3]));
          l_part[mb] += (p0 + p1) + (p2 + p3);
          bf16x4 pk = {(__bf16)p0, (__bf16)p1, (__bf16)p2, (__bf16)p3};
          *(bf16x4*)&Psw[(mb * 16 + l16) * LPs + nb * 16 + quad * 4] = pk;
        }
      }
      __asm__ volatile("s_waitcnt lgkmcnt(0)" ::: "memory");
      bf16x8 pb[2];
#pragma unroll
      for (int mb = 0; mb < 2; mb++)
        pb[mb] = *(const bf16x8*)&Psw[(mb * 16 + l16) * LPs + half * 32 + quad * 8];
      __builtin_amdgcn_s_setprio(1);
#pragma unroll
      for (int db = 0; db < 4; db++)
#pragma unroll
        for (int mb = 0; mb < 2; mb++)
          o_acc[mb][db] = __builtin_amdgcn_mfma_f32_16x16x32_bf16(va[db], pb[mb],
                                                                  o_acc[mb][db], 0, 0, 0);
      __builtin_amdgcn_s_setprio(0);
      if (half == 0) {
#pragma unroll
        for (int db = 0; db < 4; db++)
          va[db] = *(const bf16x8*)&vt[vbase + (size_t)(db * 16 + l16) * SEQ +
                                       kv0 + 32 + quad * 8];
      }
    }
  }
#pragma unroll
  for (int mb = 0; mb < 2; mb++) {
    l_part[mb] += __shfl_xor(l_part[mb], 16);
    l_part[mb] += __shfl_xor(l_part[mb], 32);
    l_part[mb] = 1.0f / l_part[mb];
  }
#pragma unroll
  for (int mb = 0; mb < 2; mb++) {
#pragma unroll
    for (int db = 0; db < 4; db++) {
      ushort4v o;
#pragma unroll
      for (int r = 0; r < 4; r++) o[r] = f2bf(o_acc[mb][db][r] * l_part[mb]);
      *(ushort4v*)&attn_out[(tok0 + qblk + mb * 16 + l16) * H + h * HDIM +
                            db * 16 + quad * 4] = o;
    }
  }
}

extern "C" void kernel_launch(void* const* d_in, const int* in_sizes, int n_in,
                              void* d_out, int out_size, void* d_ws, size_t ws_size,
                              hipStream_t stream) {
  const float* x = (const float*)d_in[0];
  const float* ln1_g = (const float*)d_in[1];
  const float* ln1_b = (const float*)d_in[2];
  const float* qkv_w = (const float*)d_in[3];
  const float* qkv_b = (const float*)d_in[4];
  const float* out_w = (const float*)d_in[5];
  const float* out_b = (const float*)d_in[6];
  const float* ln2_g = (const float*)d_in[7];
  const float* ln2_b = (const float*)d_in[8];
  const float* w1 = (const float*)d_in[9];
  const float* b1 = (const float*)d_in[10];
  const float* w2 = (const float*)d_in[11];
  const float* b2 = (const float*)d_in[12];
  float* outp = (float*)d_out;

  size_t off = 0;
  auto take = [&](size_t n) {
    char* p = (char*)d_ws + off;
    off += (n + 255) & ~(size_t)255;
    return p;
  };
  unsigned short* h1 = (unsigned short*)take((size_t)NTOK * H * 2);       // also h2
  unsigned short* qkvb = (unsigned short*)take((size_t)NTOK * 3 * H * 2); // qkv; later mid
  unsigned short* attn = (unsigned short*)take((size_t)NTOK * H * 2);
  float* x1 = (float*)take((size_t)NTOK * H * 4);
  unsigned short* qkvwt = (unsigned short*)take((size_t)3 * H * H * 2);
  unsigned short* outwt = (unsigned short*)take((size_t)H * H * 2);
  unsigned short* w1t = (unsigned short*)take((size_t)H * IDIM * 2);
  unsigned short* w2t = (unsigned short*)take((size_t)H * IDIM * 2);
  unsigned short* h2 = h1;
  unsigned short* mid = qkvb;                // [NTOK][IDIM] aliases qkv+attn exactly
  unsigned short* vt = (unsigned short*)x1;  // vt dead before proj writes x1

  dim3 tb(32, 8);
  transpose_cast_kernel<<<dim3(3 * H / 32, H / 32), tb, 0, stream>>>(qkv_w, qkvwt, H, 3 * H);
  transpose_cast_kernel<<<dim3(H / 32, H / 32), tb, 0, stream>>>(out_w, outwt, H, H);
  transpose_cast_kernel<<<dim3(IDIM / 32, H / 32), tb, 0, stream>>>(w1, w1t, H, IDIM);
  transpose_cast_kernel<<<dim3(H / 32, IDIM / 32), tb, 0, stream>>>(w2, w2t, IDIM, H);

  layernorm_kernel<<<NTOK, 256, 0, stream>>>(x, ln1_g, ln1_b, h1);
  // QKV GEMM (256^2 8-phase); v-slice blocks (n0>=2H) write vt transposed
  gemm256_kernel<0><<<dim3(3 * H / 256, NTOK / 256), 512, 0, stream>>>(
      h1, qkvwt, qkv_b, qkvb, vt, NTOK, 3 * H, H);
  flash_attn_kernel<<<dim3(SEQ / 256 * BATCH * NHEAD), 512, 0, stream>>>(qkvb, vt, attn);
  gemm_bt_kernel<2><<<dim3(H / 128, NTOK / 128), 256, 0, stream>>>(
      attn, outwt, out_b, x, x1, nullptr, NTOK, H, H);
  layernorm_kernel<<<NTOK, 256, 0, stream>>>(x1, ln2_g, ln2_b, h2);
  // MLP1 (256^2 8-phase, gelu epilogue)
  gemm256_kernel<1><<<dim3(IDIM / 256, NTOK / 256), 512, 0, stream>>>(
      h2, w1t, b1, mid, nullptr, NTOK, IDIM, H);
  gemm_bt_kernel<2><<<dim3(H / 128, NTOK / 128), 256, 0, stream>>>(
      mid, w2t, b2, x1, outp, nullptr, NTOK, H, IDIM);
}